// Round 5
// baseline (875.831 us; speedup 1.0000x reference)
//
#include <hip/hip_runtime.h>

// output element offsets (f32 elements)
#define OUT_X0   0
#define OUT_EMB  16777216
#define OUT_OPC  16781312
#define OUT_LOSS 16879616

// workspace byte offsets (total ~1.4 MB)
#define OFF_GFEAT 0            // 8192     f32 [16][128]
#define OFF_POOL  8192         // 65536    f32 [16][1024]
#define OFF_EMB   73728        // 16384    f32 [16][256]
#define OFF_HD1   90112        // 32768    f32 [16][512]
#define OFF_HD2   122880       // 65536    f32 [16][1024]
#define OFF_H3    188416       // 393216   f32 [16][6144]
#define OFF_OPC   581632       // 393216   f32 [16][6144]
#define OFF_D1M   974848       // 262144   u32 [16][4096]
#define OFF_D2M   1236992      // 131072   u32 [16][2048]
#define OFF_PS    1368064      // 384      f32 [96]

// ---------------- naive conv1+conv2: one thread per point, direct f32 x0 store ----------------
__global__ __launch_bounds__(256) void naive_x0(
    const float* __restrict__ in_pc,
    const float* __restrict__ w1, const float* __restrict__ b1,
    const float* __restrict__ w2, const float* __restrict__ b2,
    float* __restrict__ x0)
{
  int idx = blockIdx.x*256 + threadIdx.x;   // global point id, 65536 total
  int b = idx >> 12, n = idx & 4095;
  const float* p = in_pc + (size_t)idx*3;
  float px = p[0], py = p[1], pz = p[2];
  float h1[64];
  #pragma unroll
  for (int c=0;c<64;c++){
    float v = w1[c*3]*px + w1[c*3+1]*py + w1[c*3+2]*pz + b1[c];
    h1[c] = v > 0.f ? v : 0.f;
  }
  for (int o=0;o<128;o++){
    float a = b2[o];
    #pragma unroll
    for (int c=0;c<64;c++) a += w2[o*64+c]*h1[c];
    a = a > 0.f ? a : 0.f;
    x0[((size_t)b*256 + o)*4096 + n] = a;
  }
}

// ---------------- gfeat[b][c] = max_n x0[b][c][n] (block per (b,c)) ----------------
__global__ __launch_bounds__(256) void gfeat_k(
    const float* __restrict__ x0, float* __restrict__ gfeat)
{
  int b = blockIdx.x >> 7, c = blockIdx.x & 127, tid = threadIdx.x;
  const float* row = x0 + ((size_t)b*256 + c)*4096;
  float m = 0.f;
  for (int i=tid;i<4096;i+=256) m = fmaxf(m, row[i]);
  for (int off=32; off; off>>=1) m = fmaxf(m, __shfl_xor(m, off));
  __shared__ float red[4];
  if ((tid&63)==0) red[tid>>6]=m;
  __syncthreads();
  if (tid==0) gfeat[b*128+c] = fmaxf(fmaxf(red[0],red[1]), fmaxf(red[2],red[3]));
}

// ---------------- x0 second half: broadcast gfeat (f32) ----------------
__global__ __launch_bounds__(256) void gfeat_bcast(
    const float* __restrict__ gfeat, float* __restrict__ x0)
{
  unsigned U = blockIdx.x*256 + threadIdx.x;   // over 16*128*4096 f32
  int n = U & 4095;
  int c = (U >> 12) & 127;
  int b = U >> 19;
  x0[((size_t)b*256 + 128 + c)*4096 + n] = gfeat[b*128+c];
}

// ---------------- conv3 + max-pool: block per (b, 8 outputs) ----------------
__global__ __launch_bounds__(256) void conv3n(
    const float* __restrict__ x0, const float* __restrict__ gfeat,
    const float* __restrict__ w3, const float* __restrict__ b3,
    unsigned* __restrict__ pooled)
{
  __shared__ float wrow[8][256];
  int b = blockIdx.x >> 7, og = (blockIdx.x & 127)*8, tid = threadIdx.x;
  for (int i=tid;i<2048;i+=256){ int j=i>>8, c=i&255; wrow[j][c]=w3[(size_t)(og+j)*256+c]; }
  __syncthreads();
  float gconst[8];
  #pragma unroll
  for (int j=0;j<8;j++){
    float g = b3[og+j];
    for (int c=0;c<128;c++) g += gfeat[b*128+c]*wrow[j][128+c];
    gconst[j] = g;
  }
  const float* xb = x0 + (size_t)b*256*4096;
  float m[8];
  #pragma unroll
  for (int j=0;j<8;j++) m[j]=0.f;   // relu floor
  for (int n=tid;n<4096;n+=256){
    float v[8];
    #pragma unroll
    for (int j=0;j<8;j++) v[j]=gconst[j];
    for (int c=0;c<128;c++){
      float xv = xb[(size_t)c*4096 + n];
      #pragma unroll
      for (int j=0;j<8;j++) v[j] += xv*wrow[j][c];
    }
    #pragma unroll
    for (int j=0;j<8;j++) m[j] = fmaxf(m[j], v[j]);
  }
  #pragma unroll
  for (int j=0;j<8;j++){
    float v = m[j];
    for (int off=32; off; off>>=1) v = fmaxf(v, __shfl_xor(v, off));
    if ((tid&63)==0) atomicMax(&pooled[(size_t)b*1024+og+j], __float_as_uint(v));
  }
}

// ---------------- small FC: out[16][O] = A[16][K] @ W^T (+bias, relu?) ----------------
template<bool RELU>
__global__ __launch_bounds__(256) void fc_small(
    const float* __restrict__ A, const float* __restrict__ W,
    const float* __restrict__ bias, float* __restrict__ out,
    float* __restrict__ out2, int K, int O)
{
  extern __shared__ float Als[];
  int tid = threadIdx.x;
  int total = 16*K;
  for (int i=tid;i<total;i+=256) Als[i]=A[i];
  __syncthreads();
  int wid = tid>>6, lane = tid&63;
  for (int oi=0;oi<8;oi++){
    int o = blockIdx.x*32 + wid*8 + oi;
    float acc[16];
    #pragma unroll
    for (int b=0;b<16;b++) acc[b]=0.f;
    for (int i=0;i<K;i+=64){
      float wv = W[(size_t)o*K + i + lane];
      int k = i + lane;
      #pragma unroll
      for (int b=0;b<16;b++) acc[b] += Als[b*K+k]*wv;
    }
    #pragma unroll
    for (int b=0;b<16;b++){
      float v = acc[b];
      for (int off=32; off; off>>=1) v += __shfl_xor(v,off);
      if (lane==0){
        v += bias[o];
        if (RELU) v = fmaxf(v, 0.f);
        out[b*O+o] = v;
        if (out2) out2[b*O+o] = v;
      }
    }
  }
}

// ---------------- LayerNorm over 6144 per batch row ----------------
__global__ __launch_bounds__(256) void lnorm(
    const float* __restrict__ h3, const float* __restrict__ g,
    const float* __restrict__ be, float* __restrict__ outf,
    float* __restrict__ outb)
{
  int b = blockIdx.x, tid = threadIdx.x;
  const float* x = h3 + b*6144;
  float s=0.f, s2=0.f;
  for (int i=tid;i<6144;i+=256){ float v=x[i]; s+=v; s2+=v*v; }
  for (int off=32; off; off>>=1){ s += __shfl_xor(s,off); s2 += __shfl_xor(s2,off); }
  __shared__ float red[8];
  int lane = tid&63, wid = tid>>6;
  if (lane==0){ red[wid]=s; red[4+wid]=s2; }
  __syncthreads();
  s  = red[0]+red[1]+red[2]+red[3];
  s2 = red[4]+red[5]+red[6]+red[7];
  float mu  = s * (1.f/6144.f);
  float var = s2 * (1.f/6144.f) - mu*mu;
  float inv = rsqrtf(var + 1e-5f);
  for (int i=tid;i<6144;i+=256){
    float v = (x[i]-mu)*inv*g[i] + be[i];
    outf[b*6144+i] = v;
    outb[b*6144+i] = v;
  }
}

// ---------------- chamfer: row mins (each thread owns one n) ----------------
__global__ __launch_bounds__(256) void chamfer_d1(
    const float* __restrict__ in_pc, const float* __restrict__ opc,
    unsigned* __restrict__ d1m)
{
  __shared__ float qs[1536];
  int b = blockIdx.y, mt = blockIdx.z, tid = threadIdx.x;
  const float* qb = opc + b*6144 + mt*1536;
  for (int i=tid;i<1536;i+=256) qs[i]=qb[i];
  __syncthreads();
  int n = blockIdx.x*256 + tid;
  size_t base = ((size_t)b*4096 + n)*3;
  float px=in_pc[base], py=in_pc[base+1], pz=in_pc[base+2];
  float mn = 3.0e38f;
  #pragma unroll 4
  for (int m=0;m<512;m++){
    float dx=px-qs[m*3], dy=py-qs[m*3+1], dz=pz-qs[m*3+2];
    mn = fminf(mn, dx*dx + dy*dy + dz*dz);
  }
  atomicMin(&d1m[b*4096+n], __float_as_uint(mn));
}

// ---------------- chamfer: col mins (each thread owns one m) ----------------
__global__ __launch_bounds__(256) void chamfer_d2(
    const float* __restrict__ in_pc, const float* __restrict__ opc,
    unsigned* __restrict__ d2m)
{
  __shared__ float psh[3072];
  int b = blockIdx.y, nt = blockIdx.z, tid = threadIdx.x;
  size_t base = ((size_t)b*4096 + nt*1024)*3;
  for (int i=tid;i<3072;i+=256) psh[i]=in_pc[base+i];
  __syncthreads();
  int m = blockIdx.x*256 + tid;
  const float* q = opc + b*6144 + m*3;
  float qx=q[0], qy=q[1], qz=q[2];
  float mn = 3.0e38f;
  #pragma unroll 4
  for (int n=0;n<1024;n++){
    float dx=qx-psh[n*3], dy=qy-psh[n*3+1], dz=qz-psh[n*3+2];
    mn = fminf(mn, dx*dx + dy*dy + dz*dz);
  }
  atomicMin(&d2m[b*2048+m], __float_as_uint(mn));
}

// ---------------- deterministic loss reduction ----------------
__global__ __launch_bounds__(256) void sum_part(
    const unsigned* __restrict__ d1m, const unsigned* __restrict__ d2m,
    float* __restrict__ ps)
{
  int bid = blockIdx.x, tid = threadIdx.x;
  const unsigned* src = (bid<64) ? (d1m + bid*1024) : (d2m + (size_t)(bid-64)*1024);
  float s = 0.f;
  for (int i=tid;i<1024;i+=256) s += __uint_as_float(src[i]);
  for (int off=32; off; off>>=1) s += __shfl_xor(s,off);
  __shared__ float red[4];
  if ((tid&63)==0) red[tid>>6]=s;
  __syncthreads();
  if (tid==0) ps[bid] = red[0]+red[1]+red[2]+red[3];
}

__global__ void loss_k(const float* __restrict__ ps, float* __restrict__ out){
  int tid = threadIdx.x;  // 128 threads
  float v = 0.f;
  if (tid < 64) v = ps[tid] * (1.0f/65536.0f);
  else if (tid < 96) v = ps[tid] * (1.0f/32768.0f);
  for (int off=32; off; off>>=1) v += __shfl_xor(v,off);
  __shared__ float red[2];
  if ((tid&63)==0) red[tid>>6]=v;
  __syncthreads();
  if (tid==0) out[0] = red[0]+red[1];
}

// ---------------- launch ----------------
extern "C" void kernel_launch(void* const* d_in, const int* in_sizes, int n_in,
                              void* d_out, int out_size, void* d_ws, size_t ws_size,
                              hipStream_t stream)
{
  (void)in_sizes; (void)n_in; (void)out_size; (void)ws_size;
  const float* in_pc = (const float*)d_in[0];
  const float* w1   = (const float*)d_in[1];
  const float* b1   = (const float*)d_in[2];
  const float* w2   = (const float*)d_in[3];
  const float* b2   = (const float*)d_in[4];
  const float* w3   = (const float*)d_in[5];
  const float* b3   = (const float*)d_in[6];
  const float* wenc = (const float*)d_in[7];
  const float* benc = (const float*)d_in[8];
  const float* wf1  = (const float*)d_in[9];
  const float* bfc1 = (const float*)d_in[10];
  const float* wf2  = (const float*)d_in[11];
  const float* bfc2 = (const float*)d_in[12];
  const float* wf3  = (const float*)d_in[13];
  const float* bfc3 = (const float*)d_in[14];
  const float* lng  = (const float*)d_in[15];
  const float* lnb  = (const float*)d_in[16];
  float* out = (float*)d_out;

  char* ws = (char*)d_ws;
  float* gfeat = (float*)(ws + OFF_GFEAT);
  float* pooled = (float*)(ws + OFF_POOL);
  float* emb  = (float*)(ws + OFF_EMB);
  float* hd1  = (float*)(ws + OFF_HD1);
  float* hd2  = (float*)(ws + OFF_HD2);
  float* h3   = (float*)(ws + OFF_H3);
  float* opc  = (float*)(ws + OFF_OPC);
  unsigned* d1m = (unsigned*)(ws + OFF_D1M);
  unsigned* d2m = (unsigned*)(ws + OFF_D2M);
  float* ps   = (float*)(ws + OFF_PS);

  hipMemsetAsync(ws + OFF_POOL, 0, 65536, stream);               // pooled = 0
  hipMemsetAsync(ws + OFF_D1M, 0x7F, 262144 + 131072, stream);   // d1m + d2m ~ +inf

  naive_x0<<<256, 256, 0, stream>>>(in_pc, w1, b1, w2, b2, out);
  gfeat_k<<<2048, 256, 0, stream>>>(out, gfeat);
  gfeat_bcast<<<32768, 256, 0, stream>>>(gfeat, out);
  conv3n<<<2048, 256, 0, stream>>>(out, gfeat, w3, b3, (unsigned*)pooled);
  fc_small<false><<<8,   256, 16*1024*4, stream>>>(pooled, wenc, benc, emb, out + OUT_EMB, 1024, 256);
  fc_small<true ><<<16,  256, 16*256*4,  stream>>>(emb, wf1, bfc1, hd1, nullptr, 256, 512);
  fc_small<true ><<<32,  256, 16*512*4,  stream>>>(hd1, wf2, bfc2, hd2, nullptr, 512, 1024);
  fc_small<false><<<192, 256, 16*1024*4, stream>>>(hd2, wf3, bfc3, h3, nullptr, 1024, 6144);
  lnorm<<<16, 256, 0, stream>>>(h3, lng, lnb, opc, out + OUT_OPC);
  chamfer_d1<<<dim3(16,16,4), 256, 0, stream>>>(in_pc, opc, d1m);
  chamfer_d2<<<dim3(8,16,4), 256, 0, stream>>>(in_pc, opc, d2m);
  sum_part<<<96, 256, 0, stream>>>(d1m, d2m, ps);
  loss_k<<<1, 128, 0, stream>>>(ps, out + OUT_LOSS);
}

// Round 6
// 641.231 us; speedup vs baseline: 1.3659x; 1.3659x over previous
//
#include <hip/hip_runtime.h>

// output element offsets (f32 elements)
#define OUT_X0   0
#define OUT_EMB  16777216
#define OUT_OPC  16781312
#define OUT_LOSS 16879616

// small-buffer byte offsets (relative to `small` base, total ~1.4 MB)
#define OFF_GFEAT 0            // 8192     f32 [16][128]
#define OFF_POOL  8192         // 65536    f32 [16][1024]
#define OFF_GCON  73728        // 65536    f32 [16][1024]
#define OFF_EMB   139264       // 16384    f32 [16][256]
#define OFF_HD1   155648       // 32768    f32 [16][512]
#define OFF_HD2   188416       // 65536    f32 [16][1024]
#define OFF_H3    253952       // 393216   f32 [16][6144]
#define OFF_OPC   647168       // 393216   f32 [16][6144]
#define OFF_D1M   1040384      // 262144   u32 [16][4096]
#define OFF_D2M   1302528      // 131072   u32 [16][2048]
#define OFF_PS    1433600      // 384      f32 [96]
#define H2_BYTES  (16u*1024*1024)   // bf16 h2 [65536][128] at ws+0 (big path)

typedef short short8 __attribute__((ext_vector_type(8)));
typedef float f32x4  __attribute__((ext_vector_type(4)));

__device__ __forceinline__ unsigned short f2bf(float f){
  unsigned u = __float_as_uint(f);
  return (unsigned short)((u + 0x7FFFu + ((u >> 16) & 1u)) >> 16);
}

// ---------------- conv1+conv2: one thread per point; x0 f32 + optional h2 bf16 ----------------
template<bool EMIT_H2>
__global__ __launch_bounds__(256) void naive_x0(
    const float* __restrict__ in_pc,
    const float* __restrict__ w1, const float* __restrict__ b1,
    const float* __restrict__ w2, const float* __restrict__ b2,
    float* __restrict__ x0, unsigned short* __restrict__ h2b)
{
  int idx = blockIdx.x*256 + threadIdx.x;   // global point id, 65536 total
  int b = idx >> 12, n = idx & 4095;
  const float* p = in_pc + (size_t)idx*3;
  float px = p[0], py = p[1], pz = p[2];
  float h1[64];
  #pragma unroll
  for (int c=0;c<64;c++){
    float v = w1[c*3]*px + w1[c*3+1]*py + w1[c*3+2]*pz + b1[c];
    h1[c] = v > 0.f ? v : 0.f;
  }
  for (int og=0; og<16; ++og){
    unsigned short hp[8];
    #pragma unroll
    for (int j=0;j<8;j++){
      int o = og*8+j;
      float a = b2[o];
      #pragma unroll 16
      for (int c=0;c<64;c++) a += w2[o*64+c]*h1[c];
      a = a > 0.f ? a : 0.f;
      x0[((size_t)b*256 + o)*4096 + n] = a;
      hp[j] = f2bf(a);
    }
    if (EMIT_H2) *(uint4*)&h2b[(size_t)idx*128 + og*8] = *(const uint4*)hp;
  }
}

// ---------------- gfeat[b][c] = max_n x0[b][c][n] (block per (b,c)) ----------------
__global__ __launch_bounds__(256) void gfeat_k(
    const float* __restrict__ x0, float* __restrict__ gfeat)
{
  int b = blockIdx.x >> 7, c = blockIdx.x & 127, tid = threadIdx.x;
  const float* row = x0 + ((size_t)b*256 + c)*4096;
  float m = 0.f;
  for (int i=tid;i<4096;i+=256) m = fmaxf(m, row[i]);
  for (int off=32; off; off>>=1) m = fmaxf(m, __shfl_xor(m, off));
  __shared__ float red[4];
  if ((tid&63)==0) red[tid>>6]=m;
  __syncthreads();
  if (tid==0) gfeat[b*128+c] = fmaxf(fmaxf(red[0],red[1]), fmaxf(red[2],red[3]));
}

// ---------------- x0 second half: broadcast gfeat (f32) ----------------
__global__ __launch_bounds__(256) void gfeat_bcast(
    const float* __restrict__ gfeat, float* __restrict__ x0)
{
  unsigned U = blockIdx.x*256 + threadIdx.x;   // over 16*128*4096 f32
  int n = U & 4095;
  int c = (U >> 12) & 127;
  int b = U >> 19;
  x0[((size_t)b*256 + 128 + c)*4096 + n] = gfeat[b*128+c];
}

// ---------------- gcon[b][o] = b3[o] + sum_c gfeat[b][c]*w3[o][128+c] (exact f32) ----------------
__global__ __launch_bounds__(256) void gcon_k(
    const float* __restrict__ gfeat, const float* __restrict__ w3,
    const float* __restrict__ b3, float* __restrict__ gcon)
{
  __shared__ float gf[2048];
  int tid = threadIdx.x;
  for (int i=tid;i<2048;i+=256) gf[i] = gfeat[i];
  __syncthreads();
  int o = blockIdx.x*256 + tid;
  float bias = b3[o];
  float acc[16];
  #pragma unroll
  for (int b=0;b<16;b++) acc[b]=bias;
  for (int c=0;c<128;c++){
    float wv = w3[(size_t)o*256 + 128 + c];
    #pragma unroll
    for (int b=0;b<16;b++) acc[b] += gf[b*128+c]*wv;
  }
  #pragma unroll
  for (int b=0;b<16;b++) gcon[b*1024+o] = acc[b];
}

// ---------------- conv3 MFMA GEMM (256n x 128k)x(128k -> 1024o) + relu + max-pool ----------------
__global__ __launch_bounds__(512) void conv3_pool(
    const unsigned short* __restrict__ h2b, const float* __restrict__ w3,
    const float* __restrict__ gcon, unsigned* __restrict__ pooled)
{
  __shared__ unsigned short Al[256*128];
  __shared__ unsigned short Bl[256*128];
  int mt = blockIdx.x, b = blockIdx.y;
  int tid = threadIdx.x;
  { // stage A (bf16 [n][c]) — resident across nt loop
    const uint4* src = (const uint4*)(h2b + ((size_t)b*4096 + mt*256)*128);
    #pragma unroll
    for (int i=0;i<8;i++){
      int idx = i*512 + tid;
      int r = idx>>4, kc = idx&15;
      uint4 v = src[(size_t)r*16 + kc];
      int byte = (r*256 + kc*16) ^ ((r&7)<<4);
      *(uint4*)((char*)Al + byte) = v;
    }
  }
  int lane = tid & 63, wid = tid >> 6;
  int wm = wid >> 2, wn = wid & 3;       // 2x4 waves, each 128m x 64n
  int mbase = wm*128, nbase = wn*64;
  for (int nt=0; nt<4; nt++){
    if (nt) __syncthreads();
    { // stage B: Bt[col][k] = bf16(w3[(nt*256+col)*256 + k]), k<128
      #pragma unroll
      for (int i=0;i<8;i++){
        int idx = i*512 + tid;
        int c = idx>>4, kc = idx&15;
        const float4* s = (const float4*)(w3 + ((size_t)(nt*256+c)*256 + kc*8));
        float4 v0 = s[0], v1 = s[1];
        uint4 pk;
        pk.x = (unsigned)f2bf(v0.x) | ((unsigned)f2bf(v0.y)<<16);
        pk.y = (unsigned)f2bf(v0.z) | ((unsigned)f2bf(v0.w)<<16);
        pk.z = (unsigned)f2bf(v1.x) | ((unsigned)f2bf(v1.y)<<16);
        pk.w = (unsigned)f2bf(v1.z) | ((unsigned)f2bf(v1.w)<<16);
        int byte = (c*256 + kc*16) ^ ((c&7)<<4);
        *(uint4*)((char*)Bl + byte) = pk;
      }
    }
    __syncthreads();
    f32x4 acc[8][4] = {};
    #pragma unroll
    for (int ks=0;ks<4;ks++){
      int kb = (ks*32 + (lane>>4)*8)*2;
      short8 af[8], bfr[4];
      #pragma unroll
      for (int mi=0;mi<8;mi++){
        int row = mbase + mi*16 + (lane&15);
        af[mi] = *(const short8*)((const char*)Al + ((row*256 + kb) ^ ((row&7)<<4)));
      }
      #pragma unroll
      for (int ni=0;ni<4;ni++){
        int col = nbase + ni*16 + (lane&15);
        bfr[ni] = *(const short8*)((const char*)Bl + ((col*256 + kb) ^ ((col&7)<<4)));
      }
      #pragma unroll
      for (int mi=0;mi<8;mi++){
        #pragma unroll
        for (int ni=0;ni<4;ni++)
          acc[mi][ni] = __builtin_amdgcn_mfma_f32_16x16x32_bf16(af[mi], bfr[ni], acc[mi][ni], 0,0,0);
      }
    }
    // epilogue: +gcon, relu, column max over 256 rows, atomicMax
    #pragma unroll
    for (int ni=0;ni<4;ni++){
      int o = nt*256 + nbase + ni*16 + (lane&15);
      float g = gcon[b*1024 + o];
      float m = 0.f;
      #pragma unroll
      for (int mi=0;mi<8;mi++){
        f32x4 a = acc[mi][ni];
        #pragma unroll
        for (int r=0;r<4;r++){ float v = a[r]+g; m = fmaxf(m, v); }
      }
      m = fmaxf(m, 0.f);
      m = fmaxf(m, __shfl_xor(m, 16));
      m = fmaxf(m, __shfl_xor(m, 32));
      if (lane < 16) atomicMax(&pooled[(size_t)b*1024+o], __float_as_uint(m));
    }
  }
}

// ---------------- fallback conv3 + max-pool: block per (b, 8 outputs) ----------------
__global__ __launch_bounds__(256) void conv3n(
    const float* __restrict__ x0, const float* __restrict__ gfeat,
    const float* __restrict__ w3, const float* __restrict__ b3,
    unsigned* __restrict__ pooled)
{
  __shared__ float wrow[8][256];
  int b = blockIdx.x >> 7, og = (blockIdx.x & 127)*8, tid = threadIdx.x;
  for (int i=tid;i<2048;i+=256){ int j=i>>8, c=i&255; wrow[j][c]=w3[(size_t)(og+j)*256+c]; }
  __syncthreads();
  float gconst[8];
  #pragma unroll
  for (int j=0;j<8;j++){
    float g = b3[og+j];
    for (int c=0;c<128;c++) g += gfeat[b*128+c]*wrow[j][128+c];
    gconst[j] = g;
  }
  const float* xb = x0 + (size_t)b*256*4096;
  float m[8];
  #pragma unroll
  for (int j=0;j<8;j++) m[j]=0.f;
  for (int n=tid;n<4096;n+=256){
    float v[8];
    #pragma unroll
    for (int j=0;j<8;j++) v[j]=gconst[j];
    for (int c=0;c<128;c++){
      float xv = xb[(size_t)c*4096 + n];
      #pragma unroll
      for (int j=0;j<8;j++) v[j] += xv*wrow[j][c];
    }
    #pragma unroll
    for (int j=0;j<8;j++) m[j] = fmaxf(m[j], v[j]);
  }
  #pragma unroll
  for (int j=0;j<8;j++){
    float v = m[j];
    for (int off=32; off; off>>=1) v = fmaxf(v, __shfl_xor(v, off));
    if ((tid&63)==0) atomicMax(&pooled[(size_t)b*1024+og+j], __float_as_uint(v));
  }
}

// ---------------- small FC: out[16][O] = A[16][K] @ W^T (+bias, relu?) ----------------
template<bool RELU>
__global__ __launch_bounds__(256) void fc_small(
    const float* __restrict__ A, const float* __restrict__ W,
    const float* __restrict__ bias, float* __restrict__ out,
    float* __restrict__ out2, int K, int O)
{
  extern __shared__ float Als[];
  int tid = threadIdx.x;
  int total = 16*K;
  for (int i=tid;i<total;i+=256) Als[i]=A[i];
  __syncthreads();
  int wid = tid>>6, lane = tid&63;
  for (int oi=0;oi<8;oi++){
    int o = blockIdx.x*32 + wid*8 + oi;
    float acc[16];
    #pragma unroll
    for (int b=0;b<16;b++) acc[b]=0.f;
    for (int i=0;i<K;i+=64){
      float wv = W[(size_t)o*K + i + lane];
      int k = i + lane;
      #pragma unroll
      for (int b=0;b<16;b++) acc[b] += Als[b*K+k]*wv;
    }
    #pragma unroll
    for (int b=0;b<16;b++){
      float v = acc[b];
      for (int off=32; off; off>>=1) v += __shfl_xor(v,off);
      if (lane==0){
        v += bias[o];
        if (RELU) v = fmaxf(v, 0.f);
        out[b*O+o] = v;
        if (out2) out2[b*O+o] = v;
      }
    }
  }
}

// ---------------- LayerNorm over 6144 per batch row ----------------
__global__ __launch_bounds__(256) void lnorm(
    const float* __restrict__ h3, const float* __restrict__ g,
    const float* __restrict__ be, float* __restrict__ outf,
    float* __restrict__ outb)
{
  int b = blockIdx.x, tid = threadIdx.x;
  const float* x = h3 + b*6144;
  float s=0.f, s2=0.f;
  for (int i=tid;i<6144;i+=256){ float v=x[i]; s+=v; s2+=v*v; }
  for (int off=32; off; off>>=1){ s += __shfl_xor(s,off); s2 += __shfl_xor(s2,off); }
  __shared__ float red[8];
  int lane = tid&63, wid = tid>>6;
  if (lane==0){ red[wid]=s; red[4+wid]=s2; }
  __syncthreads();
  s  = red[0]+red[1]+red[2]+red[3];
  s2 = red[4]+red[5]+red[6]+red[7];
  float mu  = s * (1.f/6144.f);
  float var = s2 * (1.f/6144.f) - mu*mu;
  float inv = rsqrtf(var + 1e-5f);
  for (int i=tid;i<6144;i+=256){
    float v = (x[i]-mu)*inv*g[i] + be[i];
    outf[b*6144+i] = v;
    outb[b*6144+i] = v;
  }
}

// ---------------- chamfer: row mins ----------------
__global__ __launch_bounds__(256) void chamfer_d1(
    const float* __restrict__ in_pc, const float* __restrict__ opc,
    unsigned* __restrict__ d1m)
{
  __shared__ float qs[1536];
  int b = blockIdx.y, mt = blockIdx.z, tid = threadIdx.x;
  const float* qb = opc + b*6144 + mt*1536;
  for (int i=tid;i<1536;i+=256) qs[i]=qb[i];
  __syncthreads();
  int n = blockIdx.x*256 + tid;
  size_t base = ((size_t)b*4096 + n)*3;
  float px=in_pc[base], py=in_pc[base+1], pz=in_pc[base+2];
  float mn = 3.0e38f;
  #pragma unroll 4
  for (int m=0;m<512;m++){
    float dx=px-qs[m*3], dy=py-qs[m*3+1], dz=pz-qs[m*3+2];
    mn = fminf(mn, dx*dx + dy*dy + dz*dz);
  }
  atomicMin(&d1m[b*4096+n], __float_as_uint(mn));
}

// ---------------- chamfer: col mins ----------------
__global__ __launch_bounds__(256) void chamfer_d2(
    const float* __restrict__ in_pc, const float* __restrict__ opc,
    unsigned* __restrict__ d2m)
{
  __shared__ float psh[3072];
  int b = blockIdx.y, nt = blockIdx.z, tid = threadIdx.x;
  size_t base = ((size_t)b*4096 + nt*1024)*3;
  for (int i=tid;i<3072;i+=256) psh[i]=in_pc[base+i];
  __syncthreads();
  int m = blockIdx.x*256 + tid;
  const float* q = opc + b*6144 + m*3;
  float qx=q[0], qy=q[1], qz=q[2];
  float mn = 3.0e38f;
  #pragma unroll 4
  for (int n=0;n<1024;n++){
    float dx=qx-psh[n*3], dy=qy-psh[n*3+1], dz=qz-psh[n*3+2];
    mn = fminf(mn, dx*dx + dy*dy + dz*dz);
  }
  atomicMin(&d2m[b*2048+m], __float_as_uint(mn));
}

// ---------------- deterministic loss reduction ----------------
__global__ __launch_bounds__(256) void sum_part(
    const unsigned* __restrict__ d1m, const unsigned* __restrict__ d2m,
    float* __restrict__ ps)
{
  int bid = blockIdx.x, tid = threadIdx.x;
  const unsigned* src = (bid<64) ? (d1m + bid*1024) : (d2m + (size_t)(bid-64)*1024);
  float s = 0.f;
  for (int i=tid;i<1024;i+=256) s += __uint_as_float(src[i]);
  for (int off=32; off; off>>=1) s += __shfl_xor(s,off);
  __shared__ float red[4];
  if ((tid&63)==0) red[tid>>6]=s;
  __syncthreads();
  if (tid==0) ps[bid] = red[0]+red[1]+red[2]+red[3];
}

__global__ void loss_k(const float* __restrict__ ps, float* __restrict__ out){
  int tid = threadIdx.x;  // 128 threads
  float v = 0.f;
  if (tid < 64) v = ps[tid] * (1.0f/65536.0f);
  else if (tid < 96) v = ps[tid] * (1.0f/32768.0f);
  for (int off=32; off; off>>=1) v += __shfl_xor(v,off);
  __shared__ float red[2];
  if ((tid&63)==0) red[tid>>6]=v;
  __syncthreads();
  if (tid==0) out[0] = red[0]+red[1];
}

// ---------------- launch ----------------
extern "C" void kernel_launch(void* const* d_in, const int* in_sizes, int n_in,
                              void* d_out, int out_size, void* d_ws, size_t ws_size,
                              hipStream_t stream)
{
  (void)in_sizes; (void)n_in; (void)out_size;
  const float* in_pc = (const float*)d_in[0];
  const float* w1   = (const float*)d_in[1];
  const float* b1   = (const float*)d_in[2];
  const float* w2   = (const float*)d_in[3];
  const float* b2   = (const float*)d_in[4];
  const float* w3   = (const float*)d_in[5];
  const float* b3   = (const float*)d_in[6];
  const float* wenc = (const float*)d_in[7];
  const float* benc = (const float*)d_in[8];
  const float* wf1  = (const float*)d_in[9];
  const float* bfc1 = (const float*)d_in[10];
  const float* wf2  = (const float*)d_in[11];
  const float* bfc2 = (const float*)d_in[12];
  const float* wf3  = (const float*)d_in[13];
  const float* bfc3 = (const float*)d_in[14];
  const float* lng  = (const float*)d_in[15];
  const float* lnb  = (const float*)d_in[16];
  float* out = (float*)d_out;

  bool big = ws_size >= (size_t)(H2_BYTES + 2*1024*1024);
  char* ws = (char*)d_ws;
  unsigned short* h2b = (unsigned short*)ws;           // big path only
  char* small = ws + (big ? H2_BYTES : 0);

  float* gfeat = (float*)(small + OFF_GFEAT);
  float* pooled = (float*)(small + OFF_POOL);
  float* gcon = (float*)(small + OFF_GCON);
  float* emb  = (float*)(small + OFF_EMB);
  float* hd1  = (float*)(small + OFF_HD1);
  float* hd2  = (float*)(small + OFF_HD2);
  float* h3   = (float*)(small + OFF_H3);
  float* opc  = (float*)(small + OFF_OPC);
  unsigned* d1m = (unsigned*)(small + OFF_D1M);
  unsigned* d2m = (unsigned*)(small + OFF_D2M);
  float* ps   = (float*)(small + OFF_PS);

  hipMemsetAsync(small + OFF_POOL, 0, 65536, stream);              // pooled = 0
  hipMemsetAsync(small + OFF_D1M, 0x7F, 262144 + 131072, stream);  // d1m + d2m ~ +inf

  if (big){
    naive_x0<true ><<<256, 256, 0, stream>>>(in_pc, w1, b1, w2, b2, out, h2b);
  } else {
    naive_x0<false><<<256, 256, 0, stream>>>(in_pc, w1, b1, w2, b2, out, nullptr);
  }
  gfeat_k<<<2048, 256, 0, stream>>>(out, gfeat);
  gfeat_bcast<<<32768, 256, 0, stream>>>(gfeat, out);
  if (big){
    gcon_k<<<4, 256, 0, stream>>>(gfeat, w3, b3, gcon);
    conv3_pool<<<dim3(16,16), 512, 0, stream>>>(h2b, w3, gcon, (unsigned*)pooled);
  } else {
    conv3n<<<2048, 256, 0, stream>>>(out, gfeat, w3, b3, (unsigned*)pooled);
  }
  fc_small<false><<<8,   256, 16*1024*4, stream>>>(pooled, wenc, benc, emb, out + OUT_EMB, 1024, 256);
  fc_small<true ><<<16,  256, 16*256*4,  stream>>>(emb, wf1, bfc1, hd1, nullptr, 256, 512);
  fc_small<true ><<<32,  256, 16*512*4,  stream>>>(hd1, wf2, bfc2, hd2, nullptr, 512, 1024);
  fc_small<false><<<192, 256, 16*1024*4, stream>>>(hd2, wf3, bfc3, h3, nullptr, 1024, 6144);
  lnorm<<<16, 256, 0, stream>>>(h3, lng, lnb, opc, out + OUT_OPC);
  chamfer_d1<<<dim3(16,16,4), 256, 0, stream>>>(in_pc, opc, d1m);
  chamfer_d2<<<dim3(8,16,4), 256, 0, stream>>>(in_pc, opc, d2m);
  sum_part<<<96, 256, 0, stream>>>(d1m, d2m, ps);
  loss_k<<<1, 128, 0, stream>>>(ps, out + OUT_LOSS);
}

// Round 7
// 391.719 us; speedup vs baseline: 2.2359x; 1.6370x over previous
//
#include <hip/hip_runtime.h>

// output element offsets (f32 elements)
#define OUT_X0   0
#define OUT_EMB  16777216
#define OUT_OPC  16781312
#define OUT_LOSS 16879616

// small-buffer byte offsets (relative to `small` base)
#define OFF_GFEAT 0            // 8192     u32 float-bits [16][128]
#define OFF_POOL  8192         // 65536    u32 float-bits [16][1024]
#define OFF_GCON  73728        // 65536    f32 [16][1024]
#define OFF_EMB   139264       // 16384    f32 [16][256]
#define OFF_HD1   155648       // 32768    f32 [16][512]
#define OFF_HD2   188416       // 65536    f32 [16][1024]
#define OFF_H3    253952       // 393216   f32 [16][6144]
#define OFF_OPC   647168       // 393216   f32 [16][6144]
#define OFF_D1M   1040384      // 262144   u32 [16][4096]
#define OFF_D2M   1302528      // 131072   u32 [16][2048]
#define OFF_PS    1433600      // 384      f32 [96]
#define H2_BYTES  (16u*1024*1024)   // bf16 h2 [65536][128] at ws+0 (big path)

typedef short short8 __attribute__((ext_vector_type(8)));
typedef float f32x4  __attribute__((ext_vector_type(4)));

__device__ __forceinline__ unsigned short f2bf(float f){
  unsigned u = __float_as_uint(f);
  return (unsigned short)((u + 0x7FFFu + ((u >> 16) & 1u)) >> 16);
}

// ------- conv1+conv2: one thread/point; x0 f32 + h2 bf16 + fused gfeat max -------
template<bool EMIT_H2>
__global__ __launch_bounds__(256) void conv12(
    const float* __restrict__ in_pc,
    const float* __restrict__ w1, const float* __restrict__ b1,
    const float* __restrict__ w2, const float* __restrict__ b2,
    float* __restrict__ x0, unsigned short* __restrict__ h2b,
    unsigned* __restrict__ gfeatU)
{
  __shared__ unsigned gmax[128];
  int tid = threadIdx.x;
  if (tid < 128) gmax[tid] = 0u;
  __syncthreads();
  int idx = blockIdx.x*256 + tid;   // global point id, 65536 total
  int b = idx >> 12, n = idx & 4095;
  int lane = tid & 63;
  const float* p = in_pc + (size_t)idx*3;
  float px = p[0], py = p[1], pz = p[2];
  float h1[64];
  #pragma unroll
  for (int c=0;c<64;c++){
    float v = w1[c*3]*px + w1[c*3+1]*py + w1[c*3+2]*pz + b1[c];
    h1[c] = v > 0.f ? v : 0.f;
  }
  for (int og=0; og<16; ++og){   // og uniform; w2 reads stay scalar loads
    unsigned short hp[8];
    #pragma unroll
    for (int j=0;j<8;j++){
      int o = og*8+j;
      float a = b2[o];
      #pragma unroll
      for (int c=0;c<64;c++) a += w2[o*64+c]*h1[c];
      a = a > 0.f ? a : 0.f;
      x0[((size_t)b*256 + o)*4096 + n] = a;
      hp[j] = f2bf(a);
      float m = a;
      #pragma unroll
      for (int off=32; off; off>>=1) m = fmaxf(m, __shfl_xor(m, off));
      if (lane==0) atomicMax(&gmax[o], __float_as_uint(m));
    }
    if (EMIT_H2) *(uint4*)&h2b[(size_t)idx*128 + og*8] = *(const uint4*)hp;
  }
  __syncthreads();
  if (tid < 128) atomicMax(&gfeatU[b*128+tid], gmax[tid]);
}

// ---------------- x0 second half: broadcast gfeat (float4) ----------------
__global__ __launch_bounds__(256) void gfeat_bcast(
    const unsigned* __restrict__ gfeatU, float* __restrict__ x0)
{
  unsigned U = blockIdx.x*256 + threadIdx.x;   // over 16*128*1024 float4
  int n4 = U & 1023;
  int c  = (U >> 10) & 127;
  int b  = U >> 17;
  float g = __uint_as_float(gfeatU[b*128+c]);
  float4 v = {g,g,g,g};
  ((float4*)x0)[(((size_t)b*256 + 128 + c)*4096)/4 + n4] = v;
}

// ------- gcon[b][o] = b3[o] + sum_c gfeat[b][c]*w3[o][128+c] (exact f32) -------
__global__ __launch_bounds__(256) void gcon_k(
    const unsigned* __restrict__ gfeatU, const float* __restrict__ w3,
    const float* __restrict__ b3, float* __restrict__ gcon)
{
  __shared__ float gf[2048];
  int tid = threadIdx.x;
  for (int i=tid;i<2048;i+=256) gf[i] = __uint_as_float(gfeatU[i]);
  __syncthreads();
  int o = blockIdx.x*256 + tid;
  float bias = b3[o];
  float acc[16];
  #pragma unroll
  for (int b=0;b<16;b++) acc[b]=bias;
  for (int c=0;c<128;c++){
    float wv = w3[(size_t)o*256 + 128 + c];
    #pragma unroll
    for (int b=0;b<16;b++) acc[b] += gf[b*128+c]*wv;
  }
  #pragma unroll
  for (int b=0;b<16;b++) gcon[b*1024+o] = acc[b];
}

// ------- conv3 MFMA GEMM (256n x 128k)x(128k -> 1024o) + relu + max-pool -------
__global__ __launch_bounds__(512) void conv3_pool(
    const unsigned short* __restrict__ h2b, const float* __restrict__ w3,
    const float* __restrict__ gcon, unsigned* __restrict__ pooled)
{
  __shared__ unsigned short Al[256*128];
  __shared__ unsigned short Bl[256*128];
  int mt = blockIdx.x, b = blockIdx.y;
  int tid = threadIdx.x;
  { // stage A (bf16 [n][c]) — resident across nt loop
    const uint4* src = (const uint4*)(h2b + ((size_t)b*4096 + mt*256)*128);
    #pragma unroll
    for (int i=0;i<8;i++){
      int idx = i*512 + tid;
      int r = idx>>4, kc = idx&15;
      uint4 v = src[(size_t)r*16 + kc];
      int byte = (r*256 + kc*16) ^ ((r&7)<<4);
      *(uint4*)((char*)Al + byte) = v;
    }
  }
  int lane = tid & 63, wid = tid >> 6;
  int wm = wid >> 2, wn = wid & 3;       // 2x4 waves, each 128m x 64n
  int mbase = wm*128, nbase = wn*64;
  for (int nt=0; nt<4; nt++){
    if (nt) __syncthreads();
    { // stage B: Bt[col][k] = bf16(w3[(nt*256+col)*256 + k]), k<128
      #pragma unroll
      for (int i=0;i<8;i++){
        int idx = i*512 + tid;
        int c = idx>>4, kc = idx&15;
        const float4* s = (const float4*)(w3 + ((size_t)(nt*256+c)*256 + kc*8));
        float4 v0 = s[0], v1 = s[1];
        uint4 pk;
        pk.x = (unsigned)f2bf(v0.x) | ((unsigned)f2bf(v0.y)<<16);
        pk.y = (unsigned)f2bf(v0.z) | ((unsigned)f2bf(v0.w)<<16);
        pk.z = (unsigned)f2bf(v1.x) | ((unsigned)f2bf(v1.y)<<16);
        pk.w = (unsigned)f2bf(v1.z) | ((unsigned)f2bf(v1.w)<<16);
        int byte = (c*256 + kc*16) ^ ((c&7)<<4);
        *(uint4*)((char*)Bl + byte) = pk;
      }
    }
    __syncthreads();
    f32x4 acc[8][4] = {};
    #pragma unroll
    for (int ks=0;ks<4;ks++){
      int kb = (ks*32 + (lane>>4)*8)*2;
      short8 af[8], bfr[4];
      #pragma unroll
      for (int mi=0;mi<8;mi++){
        int row = mbase + mi*16 + (lane&15);
        af[mi] = *(const short8*)((const char*)Al + ((row*256 + kb) ^ ((row&7)<<4)));
      }
      #pragma unroll
      for (int ni=0;ni<4;ni++){
        int col = nbase + ni*16 + (lane&15);
        bfr[ni] = *(const short8*)((const char*)Bl + ((col*256 + kb) ^ ((col&7)<<4)));
      }
      #pragma unroll
      for (int mi=0;mi<8;mi++){
        #pragma unroll
        for (int ni=0;ni<4;ni++)
          acc[mi][ni] = __builtin_amdgcn_mfma_f32_16x16x32_bf16(af[mi], bfr[ni], acc[mi][ni], 0,0,0);
      }
    }
    #pragma unroll
    for (int ni=0;ni<4;ni++){
      int o = nt*256 + nbase + ni*16 + (lane&15);
      float g = gcon[b*1024 + o];
      float m = 0.f;
      #pragma unroll
      for (int mi=0;mi<8;mi++){
        f32x4 a = acc[mi][ni];
        #pragma unroll
        for (int r=0;r<4;r++){ float v = a[r]+g; m = fmaxf(m, v); }
      }
      m = fmaxf(m, 0.f);
      m = fmaxf(m, __shfl_xor(m, 16));
      m = fmaxf(m, __shfl_xor(m, 32));
      if (lane < 16) atomicMax(&pooled[(size_t)b*1024+o], __float_as_uint(m));
    }
  }
}

// ---------------- fallback conv3 + max-pool: block per (b, 8 outputs) ----------------
__global__ __launch_bounds__(256) void conv3n(
    const float* __restrict__ x0, const unsigned* __restrict__ gfeatU,
    const float* __restrict__ w3, const float* __restrict__ b3,
    unsigned* __restrict__ pooled)
{
  __shared__ float wrow[8][256];
  int b = blockIdx.x >> 7, og = (blockIdx.x & 127)*8, tid = threadIdx.x;
  for (int i=tid;i<2048;i+=256){ int j=i>>8, c=i&255; wrow[j][c]=w3[(size_t)(og+j)*256+c]; }
  __syncthreads();
  float gconst[8];
  #pragma unroll
  for (int j=0;j<8;j++){
    float g = b3[og+j];
    for (int c=0;c<128;c++) g += __uint_as_float(gfeatU[b*128+c])*wrow[j][128+c];
    gconst[j] = g;
  }
  const float* xb = x0 + (size_t)b*256*4096;
  float m[8];
  #pragma unroll
  for (int j=0;j<8;j++) m[j]=0.f;
  for (int n=tid;n<4096;n+=256){
    float v[8];
    #pragma unroll
    for (int j=0;j<8;j++) v[j]=gconst[j];
    for (int c=0;c<128;c++){
      float xv = xb[(size_t)c*4096 + n];
      #pragma unroll
      for (int j=0;j<8;j++) v[j] += xv*wrow[j][c];
    }
    #pragma unroll
    for (int j=0;j<8;j++) m[j] = fmaxf(m[j], v[j]);
  }
  #pragma unroll
  for (int j=0;j<8;j++){
    float v = m[j];
    for (int off=32; off; off>>=1) v = fmaxf(v, __shfl_xor(v, off));
    if ((tid&63)==0) atomicMax(&pooled[(size_t)b*1024+og+j], __float_as_uint(v));
  }
}

// ---------------- fc: one wave per (b,o); A[16][K] @ W^T + bias (+relu) ----------------
template<bool RELU>
__global__ __launch_bounds__(256) void fc_wave(
    const float* __restrict__ A, const float* __restrict__ W,
    const float* __restrict__ bias, float* __restrict__ out,
    float* __restrict__ out2, int K, int O)
{
  int lane = threadIdx.x & 63, w = threadIdx.x >> 6;
  int o = blockIdx.x*4 + w;
  int b = blockIdx.y;
  const float* Wr = W + (size_t)o*K;
  const float* Ar = A + (size_t)b*K;
  float acc = 0.f;
  for (int k = lane*4; k < K; k += 256){
    float4 wv = *(const float4*)&Wr[k];
    float4 av = *(const float4*)&Ar[k];
    acc += wv.x*av.x + wv.y*av.y + wv.z*av.z + wv.w*av.w;
  }
  #pragma unroll
  for (int off=32; off; off>>=1) acc += __shfl_xor(acc, off);
  if (lane==0){
    float v = acc + bias[o];
    if (RELU) v = fmaxf(v, 0.f);
    out[(size_t)b*O+o] = v;
    if (out2) out2[(size_t)b*O+o] = v;
  }
}

// ---------------- LayerNorm over 6144 per batch row ----------------
__global__ __launch_bounds__(256) void lnorm(
    const float* __restrict__ h3, const float* __restrict__ g,
    const float* __restrict__ be, float* __restrict__ outf,
    float* __restrict__ outb)
{
  int b = blockIdx.x, tid = threadIdx.x;
  const float* x = h3 + b*6144;
  float s=0.f, s2=0.f;
  for (int i=tid;i<6144;i+=256){ float v=x[i]; s+=v; s2+=v*v; }
  for (int off=32; off; off>>=1){ s += __shfl_xor(s,off); s2 += __shfl_xor(s2,off); }
  __shared__ float red[8];
  int lane = tid&63, wid = tid>>6;
  if (lane==0){ red[wid]=s; red[4+wid]=s2; }
  __syncthreads();
  s  = red[0]+red[1]+red[2]+red[3];
  s2 = red[4]+red[5]+red[6]+red[7];
  float mu  = s * (1.f/6144.f);
  float var = s2 * (1.f/6144.f) - mu*mu;
  float inv = rsqrtf(var + 1e-5f);
  for (int i=tid;i<6144;i+=256){
    float v = (x[i]-mu)*inv*g[i] + be[i];
    outf[b*6144+i] = v;
    outb[b*6144+i] = v;
  }
}

// ---------------- chamfer: row mins ----------------
__global__ __launch_bounds__(256) void chamfer_d1(
    const float* __restrict__ in_pc, const float* __restrict__ opc,
    unsigned* __restrict__ d1m)
{
  __shared__ float qs[1536];
  int b = blockIdx.y, mt = blockIdx.z, tid = threadIdx.x;
  const float* qb = opc + b*6144 + mt*1536;
  for (int i=tid;i<1536;i+=256) qs[i]=qb[i];
  __syncthreads();
  int n = blockIdx.x*256 + tid;
  size_t base = ((size_t)b*4096 + n)*3;
  float px=in_pc[base], py=in_pc[base+1], pz=in_pc[base+2];
  float mn = 3.0e38f;
  #pragma unroll 4
  for (int m=0;m<512;m++){
    float dx=px-qs[m*3], dy=py-qs[m*3+1], dz=pz-qs[m*3+2];
    mn = fminf(mn, dx*dx + dy*dy + dz*dz);
  }
  atomicMin(&d1m[b*4096+n], __float_as_uint(mn));
}

// ---------------- chamfer: col mins ----------------
__global__ __launch_bounds__(256) void chamfer_d2(
    const float* __restrict__ in_pc, const float* __restrict__ opc,
    unsigned* __restrict__ d2m)
{
  __shared__ float psh[3072];
  int b = blockIdx.y, nt = blockIdx.z, tid = threadIdx.x;
  size_t base = ((size_t)b*4096 + nt*1024)*3;
  for (int i=tid;i<3072;i+=256) psh[i]=in_pc[base+i];
  __syncthreads();
  int m = blockIdx.x*256 + tid;
  const float* q = opc + b*6144 + m*3;
  float qx=q[0], qy=q[1], qz=q[2];
  float mn = 3.0e38f;
  #pragma unroll 4
  for (int n=0;n<1024;n++){
    float dx=qx-psh[n*3], dy=qy-psh[n*3+1], dz=qz-psh[n*3+2];
    mn = fminf(mn, dx*dx + dy*dy + dz*dz);
  }
  atomicMin(&d2m[b*2048+m], __float_as_uint(mn));
}

// ---------------- deterministic loss reduction ----------------
__global__ __launch_bounds__(256) void sum_part(
    const unsigned* __restrict__ d1m, const unsigned* __restrict__ d2m,
    float* __restrict__ ps)
{
  int bid = blockIdx.x, tid = threadIdx.x;
  const unsigned* src = (bid<64) ? (d1m + bid*1024) : (d2m + (size_t)(bid-64)*1024);
  float s = 0.f;
  for (int i=tid;i<1024;i+=256) s += __uint_as_float(src[i]);
  for (int off=32; off; off>>=1) s += __shfl_xor(s,off);
  __shared__ float red[4];
  if ((tid&63)==0) red[tid>>6]=s;
  __syncthreads();
  if (tid==0) ps[bid] = red[0]+red[1]+red[2]+red[3];
}

__global__ void loss_k(const float* __restrict__ ps, float* __restrict__ out){
  int tid = threadIdx.x;  // 128 threads
  float v = 0.f;
  if (tid < 64) v = ps[tid] * (1.0f/65536.0f);
  else if (tid < 96) v = ps[tid] * (1.0f/32768.0f);
  for (int off=32; off; off>>=1) v += __shfl_xor(v,off);
  __shared__ float red[2];
  if ((tid&63)==0) red[tid>>6]=v;
  __syncthreads();
  if (tid==0) out[0] = red[0]+red[1];
}

// ---------------- launch ----------------
extern "C" void kernel_launch(void* const* d_in, const int* in_sizes, int n_in,
                              void* d_out, int out_size, void* d_ws, size_t ws_size,
                              hipStream_t stream)
{
  (void)in_sizes; (void)n_in; (void)out_size;
  const float* in_pc = (const float*)d_in[0];
  const float* w1   = (const float*)d_in[1];
  const float* b1   = (const float*)d_in[2];
  const float* w2   = (const float*)d_in[3];
  const float* b2   = (const float*)d_in[4];
  const float* w3   = (const float*)d_in[5];
  const float* b3   = (const float*)d_in[6];
  const float* wenc = (const float*)d_in[7];
  const float* benc = (const float*)d_in[8];
  const float* wf1  = (const float*)d_in[9];
  const float* bfc1 = (const float*)d_in[10];
  const float* wf2  = (const float*)d_in[11];
  const float* bfc2 = (const float*)d_in[12];
  const float* wf3  = (const float*)d_in[13];
  const float* bfc3 = (const float*)d_in[14];
  const float* lng  = (const float*)d_in[15];
  const float* lnb  = (const float*)d_in[16];
  float* out = (float*)d_out;

  bool big = ws_size >= (size_t)(H2_BYTES + 2*1024*1024);
  char* ws = (char*)d_ws;
  unsigned short* h2b = (unsigned short*)ws;           // big path only
  char* small = ws + (big ? H2_BYTES : 0);

  unsigned* gfeatU = (unsigned*)(small + OFF_GFEAT);
  float* pooled = (float*)(small + OFF_POOL);
  float* gcon = (float*)(small + OFF_GCON);
  float* emb  = (float*)(small + OFF_EMB);
  float* hd1  = (float*)(small + OFF_HD1);
  float* hd2  = (float*)(small + OFF_HD2);
  float* h3   = (float*)(small + OFF_H3);
  float* opc  = (float*)(small + OFF_OPC);
  unsigned* d1m = (unsigned*)(small + OFF_D1M);
  unsigned* d2m = (unsigned*)(small + OFF_D2M);
  float* ps   = (float*)(small + OFF_PS);

  hipMemsetAsync(small + OFF_GFEAT, 0, 8192 + 65536, stream);      // gfeat + pooled = 0
  hipMemsetAsync(small + OFF_D1M, 0x7F, 262144 + 131072, stream);  // d1m + d2m ~ +inf

  if (big){
    conv12<true ><<<256, 256, 0, stream>>>(in_pc, w1, b1, w2, b2, out, h2b, gfeatU);
  } else {
    conv12<false><<<256, 256, 0, stream>>>(in_pc, w1, b1, w2, b2, out, nullptr, gfeatU);
  }
  gfeat_bcast<<<8192, 256, 0, stream>>>(gfeatU, out);
  if (big){
    gcon_k<<<4, 256, 0, stream>>>(gfeatU, w3, b3, gcon);
    conv3_pool<<<dim3(16,16), 512, 0, stream>>>(h2b, w3, gcon, (unsigned*)pooled);
  } else {
    conv3n<<<2048, 256, 0, stream>>>(out, gfeatU, w3, b3, (unsigned*)pooled);
  }
  fc_wave<false><<<dim3(64,16),   256, 0, stream>>>(pooled, wenc, benc, emb, out + OUT_EMB, 1024, 256);
  fc_wave<true ><<<dim3(128,16),  256, 0, stream>>>(emb, wf1, bfc1, hd1, nullptr, 256, 512);
  fc_wave<true ><<<dim3(256,16),  256, 0, stream>>>(hd1, wf2, bfc2, hd2, nullptr, 512, 1024);
  fc_wave<false><<<dim3(1536,16), 256, 0, stream>>>(hd2, wf3, bfc3, h3, nullptr, 1024, 6144);
  lnorm<<<16, 256, 0, stream>>>(h3, lng, lnb, opc, out + OUT_OPC);
  chamfer_d1<<<dim3(16,16,4), 256, 0, stream>>>(in_pc, opc, d1m);
  chamfer_d2<<<dim3(8,16,4), 256, 0, stream>>>(in_pc, opc, d2m);
  sum_part<<<96, 256, 0, stream>>>(d1m, d2m, ps);
  loss_k<<<1, 128, 0, stream>>>(ps, out + OUT_LOSS);
}

// Round 8
// 227.151 us; speedup vs baseline: 3.8557x; 1.7245x over previous
//
#include <hip/hip_runtime.h>

// output element offsets (f32 elements)
#define OUT_X0   0
#define OUT_EMB  16777216
#define OUT_OPC  16781312
#define OUT_LOSS 16879616

// small-buffer byte offsets (relative to `small` base)
#define OFF_GFEAT 0            // 8192     u32 float-bits [16][128]
#define OFF_POOL  8192         // 65536    u32 float-bits [16][1024]
#define OFF_GCON  73728        // 65536    f32 [16][1024]
#define OFF_EMB   139264       // 16384    f32 [16][256]
#define OFF_HD1   155648       // 32768    f32 [16][512]
#define OFF_HD2   188416       // 65536    f32 [16][1024]
#define OFF_H3    253952       // 393216   f32 [16][6144]
#define OFF_OPC   647168       // 393216   f32 [16][6144]
#define OFF_D1M   1040384      // 262144   u32 [16][4096]
#define OFF_D2M   1302528      // 131072   u32 [16][2048]
#define OFF_PS    1433600      // 384      f32 [96]
#define OFF_W3BF  1433984      // 524288   bf16 w3 [1024][256]
#define H2_BYTES  (16u*1024*1024)   // bf16 h2 [65536][128] at ws+0 (big path)

typedef short short8 __attribute__((ext_vector_type(8)));
typedef float f32x4  __attribute__((ext_vector_type(4)));

__device__ __forceinline__ unsigned short f2bf(float f){
  unsigned u = __float_as_uint(f);
  return (unsigned short)((u + 0x7FFFu + ((u >> 16) & 1u)) >> 16);
}

// ------- conv1+conv2: block = (256 points x 16 outputs); fused gfeat max -------
template<bool EMIT_H2>
__global__ __launch_bounds__(256) void conv12(
    const float* __restrict__ in_pc,
    const float* __restrict__ w1, const float* __restrict__ b1,
    const float* __restrict__ w2, const float* __restrict__ b2,
    float* __restrict__ x0, unsigned short* __restrict__ h2b,
    unsigned* __restrict__ gfeatU)
{
  __shared__ unsigned gmax[16];
  int tid = threadIdx.x;
  if (tid < 16) gmax[tid] = 0u;
  __syncthreads();
  int idx = blockIdx.x*256 + tid;   // global point id, 65536 total
  int b = idx >> 12, n = idx & 4095;
  int gy = blockIdx.y;              // outputs [gy*16, gy*16+16)
  int lane = tid & 63;
  const float* p = in_pc + (size_t)idx*3;
  float px = p[0], py = p[1], pz = p[2];
  float h1[64];
  #pragma unroll
  for (int c=0;c<64;c++){
    float v = w1[c*3]*px + w1[c*3+1]*py + w1[c*3+2]*pz + b1[c];
    h1[c] = fmaxf(v, 0.f);
  }
  #pragma unroll
  for (int jj=0;jj<2;jj++){
    unsigned short hp[8];
    #pragma unroll
    for (int j=0;j<8;j++){
      int o = gy*16 + jj*8 + j;
      float a = b2[o];
      #pragma unroll
      for (int c=0;c<64;c++) a += w2[o*64+c]*h1[c];
      a = fmaxf(a, 0.f);
      x0[((size_t)b*256 + o)*4096 + n] = a;
      hp[j] = f2bf(a);
      float m = a;
      #pragma unroll
      for (int off=32; off; off>>=1) m = fmaxf(m, __shfl_xor(m, off));
      if (lane==0) atomicMax(&gmax[jj*8+j], __float_as_uint(m));
    }
    if (EMIT_H2) *(uint4*)&h2b[(size_t)idx*128 + gy*16 + jj*8] = *(const uint4*)hp;
  }
  __syncthreads();
  if (tid < 16) atomicMax(&gfeatU[b*128 + gy*16 + tid], gmax[tid]);
}

// ---------------- x0 second half: broadcast gfeat (float4) ----------------
__global__ __launch_bounds__(256) void gfeat_bcast(
    const unsigned* __restrict__ gfeatU, float* __restrict__ x0)
{
  unsigned U = blockIdx.x*256 + threadIdx.x;   // over 16*128*1024 float4
  int n4 = U & 1023;
  int c  = (U >> 10) & 127;
  int b  = U >> 17;
  float g = __uint_as_float(gfeatU[b*128+c]);
  float4 v = {g,g,g,g};
  ((float4*)x0)[(((size_t)b*256 + 128 + c)*4096)/4 + n4] = v;
}

// ---------------- w3 f32 -> bf16 pre-pass ----------------
__global__ __launch_bounds__(256) void w3_cvt(
    const float* __restrict__ w3, unsigned* __restrict__ w3bf)
{
  int i = blockIdx.x*256 + threadIdx.x;   // over 131072 float2
  float2 v = ((const float2*)w3)[i];
  w3bf[i] = (unsigned)f2bf(v.x) | ((unsigned)f2bf(v.y)<<16);
}

// ------- gcon[b][o] = b3[o] + sum_c gfeat[b][c]*w3[o][128+c] (exact f32) -------
__global__ __launch_bounds__(256) void gcon_k(
    const unsigned* __restrict__ gfeatU, const float* __restrict__ w3,
    const float* __restrict__ b3, float* __restrict__ gcon)
{
  __shared__ float gf[2048];
  int tid = threadIdx.x;
  for (int i=tid;i<2048;i+=256) gf[i] = __uint_as_float(gfeatU[i]);
  __syncthreads();
  int o = blockIdx.x*256 + tid;
  float bias = b3[o];
  float acc[16];
  #pragma unroll
  for (int b=0;b<16;b++) acc[b]=bias;
  for (int c=0;c<128;c++){
    float wv = w3[(size_t)o*256 + 128 + c];
    #pragma unroll
    for (int b=0;b<16;b++) acc[b] += gf[b*128+c]*wv;
  }
  #pragma unroll
  for (int b=0;b<16;b++) gcon[b*1024+o] = acc[b];
}

// ------- conv3 MFMA GEMM (256n x 128k)x(128k -> 1024o) + relu + max-pool -------
__global__ __launch_bounds__(512) void conv3_pool(
    const unsigned short* __restrict__ h2b, const unsigned short* __restrict__ w3b,
    const float* __restrict__ gcon, unsigned* __restrict__ pooled)
{
  __shared__ unsigned short Al[256*128];
  __shared__ unsigned short Bl[256*128];
  int mt = blockIdx.x, b = blockIdx.y;
  int tid = threadIdx.x;
  { // stage A (bf16 [n][c]) — resident across nt loop
    const uint4* src = (const uint4*)(h2b + ((size_t)b*4096 + mt*256)*128);
    #pragma unroll
    for (int i=0;i<8;i++){
      int idx = i*512 + tid;
      int r = idx>>4, kc = idx&15;
      uint4 v = src[(size_t)r*16 + kc];
      int byte = (r*256 + kc*16) ^ ((r&7)<<4);
      *(uint4*)((char*)Al + byte) = v;
    }
  }
  int lane = tid & 63, wid = tid >> 6;
  int wm = wid >> 2, wn = wid & 3;       // 2x4 waves, each 128m x 64n
  int mbase = wm*128, nbase = wn*64;
  for (int nt=0; nt<4; nt++){
    if (nt) __syncthreads();
    { // stage B: Bl[col][k] = w3bf[(nt*256+col)*256 + k], k<128
      #pragma unroll
      for (int i=0;i<8;i++){
        int idx = i*512 + tid;
        int c = idx>>4, kc = idx&15;
        uint4 v = *(const uint4*)(w3b + ((size_t)(nt*256+c)*256 + kc*8));
        int byte = (c*256 + kc*16) ^ ((c&7)<<4);
        *(uint4*)((char*)Bl + byte) = v;
      }
    }
    __syncthreads();
    f32x4 acc[8][4] = {};
    #pragma unroll
    for (int ks=0;ks<4;ks++){
      int kb = (ks*32 + (lane>>4)*8)*2;
      short8 af[8], bfr[4];
      #pragma unroll
      for (int mi=0;mi<8;mi++){
        int row = mbase + mi*16 + (lane&15);
        af[mi] = *(const short8*)((const char*)Al + ((row*256 + kb) ^ ((row&7)<<4)));
      }
      #pragma unroll
      for (int ni=0;ni<4;ni++){
        int col = nbase + ni*16 + (lane&15);
        bfr[ni] = *(const short8*)((const char*)Bl + ((col*256 + kb) ^ ((col&7)<<4)));
      }
      #pragma unroll
      for (int mi=0;mi<8;mi++){
        #pragma unroll
        for (int ni=0;ni<4;ni++)
          acc[mi][ni] = __builtin_amdgcn_mfma_f32_16x16x32_bf16(af[mi], bfr[ni], acc[mi][ni], 0,0,0);
      }
    }
    #pragma unroll
    for (int ni=0;ni<4;ni++){
      int o = nt*256 + nbase + ni*16 + (lane&15);
      float g = gcon[b*1024 + o];
      float m = 0.f;
      #pragma unroll
      for (int mi=0;mi<8;mi++){
        f32x4 a = acc[mi][ni];
        #pragma unroll
        for (int r=0;r<4;r++){ float v = a[r]+g; m = fmaxf(m, v); }
      }
      m = fmaxf(m, 0.f);
      m = fmaxf(m, __shfl_xor(m, 16));
      m = fmaxf(m, __shfl_xor(m, 32));
      if (lane < 16) atomicMax(&pooled[(size_t)b*1024+o], __float_as_uint(m));
    }
  }
}

// ---------------- fallback conv3 + max-pool: block per (b, 8 outputs) ----------------
__global__ __launch_bounds__(256) void conv3n(
    const float* __restrict__ x0, const unsigned* __restrict__ gfeatU,
    const float* __restrict__ w3, const float* __restrict__ b3,
    unsigned* __restrict__ pooled)
{
  __shared__ float wrow[8][256];
  int b = blockIdx.x >> 7, og = (blockIdx.x & 127)*8, tid = threadIdx.x;
  for (int i=tid;i<2048;i+=256){ int j=i>>8, c=i&255; wrow[j][c]=w3[(size_t)(og+j)*256+c]; }
  __syncthreads();
  float gconst[8];
  #pragma unroll
  for (int j=0;j<8;j++){
    float g = b3[og+j];
    for (int c=0;c<128;c++) g += __uint_as_float(gfeatU[b*128+c])*wrow[j][128+c];
    gconst[j] = g;
  }
  const float* xb = x0 + (size_t)b*256*4096;
  float m[8];
  #pragma unroll
  for (int j=0;j<8;j++) m[j]=0.f;
  for (int n=tid;n<4096;n+=256){
    float v[8];
    #pragma unroll
    for (int j=0;j<8;j++) v[j]=gconst[j];
    for (int c=0;c<128;c++){
      float xv = xb[(size_t)c*4096 + n];
      #pragma unroll
      for (int j=0;j<8;j++) v[j] += xv*wrow[j][c];
    }
    #pragma unroll
    for (int j=0;j<8;j++) m[j] = fmaxf(m[j], v[j]);
  }
  #pragma unroll
  for (int j=0;j<8;j++){
    float v = m[j];
    for (int off=32; off; off>>=1) v = fmaxf(v, __shfl_xor(v, off));
    if ((tid&63)==0) atomicMax(&pooled[(size_t)b*1024+og+j], __float_as_uint(v));
  }
}

// ------- fc: one wave per output o, all 16 batches in registers; W read once -------
template<bool RELU>
__global__ __launch_bounds__(256) void fc_wave16(
    const float* __restrict__ A, const float* __restrict__ W,
    const float* __restrict__ bias, float* __restrict__ out,
    float* __restrict__ out2, int K, int O)
{
  int lane = threadIdx.x & 63, w = threadIdx.x >> 6;
  int o = blockIdx.x*4 + w;
  const float* Wr = W + (size_t)o*K;
  float acc[16];
  #pragma unroll
  for (int b=0;b<16;b++) acc[b]=0.f;
  for (int k = lane*4; k < K; k += 256){
    float4 wv = *(const float4*)&Wr[k];
    #pragma unroll
    for (int b=0;b<16;b++){
      float4 av = *(const float4*)&A[(size_t)b*K + k];
      acc[b] += wv.x*av.x + wv.y*av.y + wv.z*av.z + wv.w*av.w;
    }
  }
  #pragma unroll
  for (int b=0;b<16;b++){
    float v = acc[b];
    #pragma unroll
    for (int off=32; off; off>>=1) v += __shfl_xor(v, off);
    if (lane==0){
      v += bias[o];
      if (RELU) v = fmaxf(v, 0.f);
      out[(size_t)b*O+o] = v;
      if (out2) out2[(size_t)b*O+o] = v;
    }
  }
}

// ---------------- LayerNorm over 6144 per batch row ----------------
__global__ __launch_bounds__(256) void lnorm(
    const float* __restrict__ h3, const float* __restrict__ g,
    const float* __restrict__ be, float* __restrict__ outf,
    float* __restrict__ outb)
{
  int b = blockIdx.x, tid = threadIdx.x;
  const float* x = h3 + b*6144;
  float s=0.f, s2=0.f;
  for (int i=tid;i<6144;i+=256){ float v=x[i]; s+=v; s2+=v*v; }
  for (int off=32; off; off>>=1){ s += __shfl_xor(s,off); s2 += __shfl_xor(s2,off); }
  __shared__ float red[8];
  int lane = tid&63, wid = tid>>6;
  if (lane==0){ red[wid]=s; red[4+wid]=s2; }
  __syncthreads();
  s  = red[0]+red[1]+red[2]+red[3];
  s2 = red[4]+red[5]+red[6]+red[7];
  float mu  = s * (1.f/6144.f);
  float var = s2 * (1.f/6144.f) - mu*mu;
  float inv = rsqrtf(var + 1e-5f);
  for (int i=tid;i<6144;i+=256){
    float v = (x[i]-mu)*inv*g[i] + be[i];
    outf[b*6144+i] = v;
    outb[b*6144+i] = v;
  }
}

// ---------------- chamfer: row mins (SoA LDS, 4x unrolled) ----------------
__global__ __launch_bounds__(256) void chamfer_d1(
    const float* __restrict__ in_pc, const float* __restrict__ opc,
    unsigned* __restrict__ d1m)
{
  __shared__ float qx[512], qy[512], qz[512];
  int b = blockIdx.y, mt = blockIdx.z, tid = threadIdx.x;
  const float* qb = opc + b*6144 + mt*1536;
  for (int i=tid;i<512;i+=256){ qx[i]=qb[i*3]; qy[i]=qb[i*3+1]; qz[i]=qb[i*3+2]; }
  __syncthreads();
  int n = blockIdx.x*256 + tid;
  size_t base = ((size_t)b*4096 + n)*3;
  float px=in_pc[base], py=in_pc[base+1], pz=in_pc[base+2];
  float mn = 3.0e38f;
  for (int m4=0;m4<128;m4++){
    float4 X = *(const float4*)&qx[m4*4];
    float4 Y = *(const float4*)&qy[m4*4];
    float4 Z = *(const float4*)&qz[m4*4];
    float dx,dy,dz,d;
    dx=px-X.x; dy=py-Y.x; dz=pz-Z.x; d=dx*dx+dy*dy+dz*dz; mn=fminf(mn,d);
    dx=px-X.y; dy=py-Y.y; dz=pz-Z.y; d=dx*dx+dy*dy+dz*dz; mn=fminf(mn,d);
    dx=px-X.z; dy=py-Y.z; dz=pz-Z.z; d=dx*dx+dy*dy+dz*dz; mn=fminf(mn,d);
    dx=px-X.w; dy=py-Y.w; dz=pz-Z.w; d=dx*dx+dy*dy+dz*dz; mn=fminf(mn,d);
  }
  atomicMin(&d1m[b*4096+n], __float_as_uint(mn));
}

// ---------------- chamfer: col mins (SoA LDS, 4x unrolled) ----------------
__global__ __launch_bounds__(256) void chamfer_d2(
    const float* __restrict__ in_pc, const float* __restrict__ opc,
    unsigned* __restrict__ d2m)
{
  __shared__ float sx[1024], sy[1024], sz[1024];
  int b = blockIdx.y, nt = blockIdx.z, tid = threadIdx.x;
  size_t base = ((size_t)b*4096 + nt*1024)*3;
  for (int i=tid;i<1024;i+=256){
    sx[i]=in_pc[base+i*3]; sy[i]=in_pc[base+i*3+1]; sz[i]=in_pc[base+i*3+2];
  }
  __syncthreads();
  int m = blockIdx.x*256 + tid;
  const float* q = opc + b*6144 + m*3;
  float qx=q[0], qy=q[1], qz=q[2];
  float mn = 3.0e38f;
  for (int n4=0;n4<256;n4++){
    float4 X = *(const float4*)&sx[n4*4];
    float4 Y = *(const float4*)&sy[n4*4];
    float4 Z = *(const float4*)&sz[n4*4];
    float dx,dy,dz,d;
    dx=qx-X.x; dy=qy-Y.x; dz=qz-Z.x; d=dx*dx+dy*dy+dz*dz; mn=fminf(mn,d);
    dx=qx-X.y; dy=qy-Y.y; dz=qz-Z.y; d=dx*dx+dy*dy+dz*dz; mn=fminf(mn,d);
    dx=qx-X.z; dy=qy-Y.z; dz=qz-Z.z; d=dx*dx+dy*dy+dz*dz; mn=fminf(mn,d);
    dx=qx-X.w; dy=qy-Y.w; dz=qz-Z.w; d=dx*dx+dy*dy+dz*dz; mn=fminf(mn,d);
  }
  atomicMin(&d2m[b*2048+m], __float_as_uint(mn));
}

// ---------------- deterministic loss reduction ----------------
__global__ __launch_bounds__(256) void sum_part(
    const unsigned* __restrict__ d1m, const unsigned* __restrict__ d2m,
    float* __restrict__ ps)
{
  int bid = blockIdx.x, tid = threadIdx.x;
  const unsigned* src = (bid<64) ? (d1m + bid*1024) : (d2m + (size_t)(bid-64)*1024);
  float s = 0.f;
  for (int i=tid;i<1024;i+=256) s += __uint_as_float(src[i]);
  for (int off=32; off; off>>=1) s += __shfl_xor(s,off);
  __shared__ float red[4];
  if ((tid&63)==0) red[tid>>6]=s;
  __syncthreads();
  if (tid==0) ps[bid] = red[0]+red[1]+red[2]+red[3];
}

__global__ void loss_k(const float* __restrict__ ps, float* __restrict__ out){
  int tid = threadIdx.x;  // 128 threads
  float v = 0.f;
  if (tid < 64) v = ps[tid] * (1.0f/65536.0f);
  else if (tid < 96) v = ps[tid] * (1.0f/32768.0f);
  for (int off=32; off; off>>=1) v += __shfl_xor(v,off);
  __shared__ float red[2];
  if ((tid&63)==0) red[tid>>6]=v;
  __syncthreads();
  if (tid==0) out[0] = red[0]+red[1];
}

// ---------------- launch ----------------
extern "C" void kernel_launch(void* const* d_in, const int* in_sizes, int n_in,
                              void* d_out, int out_size, void* d_ws, size_t ws_size,
                              hipStream_t stream)
{
  (void)in_sizes; (void)n_in; (void)out_size;
  const float* in_pc = (const float*)d_in[0];
  const float* w1   = (const float*)d_in[1];
  const float* b1   = (const float*)d_in[2];
  const float* w2   = (const float*)d_in[3];
  const float* b2   = (const float*)d_in[4];
  const float* w3   = (const float*)d_in[5];
  const float* b3   = (const float*)d_in[6];
  const float* wenc = (const float*)d_in[7];
  const float* benc = (const float*)d_in[8];
  const float* wf1  = (const float*)d_in[9];
  const float* bfc1 = (const float*)d_in[10];
  const float* wf2  = (const float*)d_in[11];
  const float* bfc2 = (const float*)d_in[12];
  const float* wf3  = (const float*)d_in[13];
  const float* bfc3 = (const float*)d_in[14];
  const float* lng  = (const float*)d_in[15];
  const float* lnb  = (const float*)d_in[16];
  float* out = (float*)d_out;

  bool big = ws_size >= (size_t)(H2_BYTES + 2*1024*1024);
  char* ws = (char*)d_ws;
  unsigned short* h2b = (unsigned short*)ws;           // big path only
  char* small = ws + (big ? H2_BYTES : 0);

  unsigned* gfeatU = (unsigned*)(small + OFF_GFEAT);
  float* pooled = (float*)(small + OFF_POOL);
  float* gcon = (float*)(small + OFF_GCON);
  float* emb  = (float*)(small + OFF_EMB);
  float* hd1  = (float*)(small + OFF_HD1);
  float* hd2  = (float*)(small + OFF_HD2);
  float* h3   = (float*)(small + OFF_H3);
  float* opc  = (float*)(small + OFF_OPC);
  unsigned* d1m = (unsigned*)(small + OFF_D1M);
  unsigned* d2m = (unsigned*)(small + OFF_D2M);
  float* ps   = (float*)(small + OFF_PS);
  unsigned short* w3b = (unsigned short*)(small + OFF_W3BF);

  hipMemsetAsync(small + OFF_GFEAT, 0, 8192 + 65536, stream);      // gfeat + pooled = 0
  hipMemsetAsync(small + OFF_D1M, 0x7F, 262144 + 131072, stream);  // d1m + d2m ~ +inf

  if (big){
    w3_cvt<<<512, 256, 0, stream>>>(w3, (unsigned*)w3b);
    conv12<true ><<<dim3(256,8), 256, 0, stream>>>(in_pc, w1, b1, w2, b2, out, h2b, gfeatU);
  } else {
    conv12<false><<<dim3(256,8), 256, 0, stream>>>(in_pc, w1, b1, w2, b2, out, nullptr, gfeatU);
  }
  gfeat_bcast<<<8192, 256, 0, stream>>>(gfeatU, out);
  if (big){
    gcon_k<<<4, 256, 0, stream>>>(gfeatU, w3, b3, gcon);
    conv3_pool<<<dim3(16,16), 512, 0, stream>>>(h2b, w3b, gcon, (unsigned*)pooled);
  } else {
    conv3n<<<2048, 256, 0, stream>>>(out, gfeatU, w3, b3, (unsigned*)pooled);
  }
  fc_wave16<false><<<64,   256, 0, stream>>>(pooled, wenc, benc, emb, out + OUT_EMB, 1024, 256);
  fc_wave16<true ><<<128,  256, 0, stream>>>(emb, wf1, bfc1, hd1, nullptr, 256, 512);
  fc_wave16<true ><<<256,  256, 0, stream>>>(hd1, wf2, bfc2, hd2, nullptr, 512, 1024);
  fc_wave16<false><<<1536, 256, 0, stream>>>(hd2, wf3, bfc3, h3, nullptr, 1024, 6144);
  lnorm<<<16, 256, 0, stream>>>(h3, lng, lnb, opc, out + OUT_OPC);
  chamfer_d1<<<dim3(16,16,4), 256, 0, stream>>>(in_pc, opc, d1m);
  chamfer_d2<<<dim3(8,16,4), 256, 0, stream>>>(in_pc, opc, d2m);
  sum_part<<<96, 256, 0, stream>>>(d1m, d2m, ps);
  loss_k<<<1, 128, 0, stream>>>(ps, out + OUT_LOSS);
}

// Round 9
// 221.817 us; speedup vs baseline: 3.9484x; 1.0240x over previous
//
#include <hip/hip_runtime.h>

// output element offsets (f32 elements)
#define OUT_X0   0
#define OUT_EMB  16777216
#define OUT_OPC  16781312
#define OUT_LOSS 16879616

// small-buffer byte offsets (relative to `small` base)
#define OFF_GFEAT 0            // 8192     u32 float-bits [16][128]
#define OFF_POOL  8192         // 65536    u32 float-bits [16][1024]
#define OFF_GCON  73728        // 65536    f32 [16][1024]
#define OFF_EMB   139264       // 16384    f32 [16][256]
#define OFF_HD1   155648       // 32768    f32 [16][512]
#define OFF_HD2   188416       // 65536    f32 [16][1024]
#define OFF_H3    253952       // 393216   f32 [16][6144]
#define OFF_OPC   647168       // 393216   f32 [16][6144]
#define OFF_D1M   1040384      // 262144   u32 [16][4096]
#define OFF_D2M   1302528      // 131072   u32 [16][2048]
#define OFF_PS    1433600      // 384      f32 [96]
#define OFF_W3BF  1433984      // 524288   bf16 w3 [1024][256]
#define H2_BYTES  (16u*1024*1024)   // bf16 h2 [65536][128] at ws+0 (big path)

typedef short short8 __attribute__((ext_vector_type(8)));
typedef float f32x4  __attribute__((ext_vector_type(4)));

__device__ __forceinline__ unsigned short f2bf(float f){
  unsigned u = __float_as_uint(f);
  return (unsigned short)((u + 0x7FFFu + ((u >> 16) & 1u)) >> 16);
}

// ------- conv1+conv2: 2 points/thread, 32 outs/block; fused gfeat max -------
template<bool EMIT_H2>
__global__ __launch_bounds__(256) void conv12(
    const float* __restrict__ in_pc,
    const float* __restrict__ w1, const float* __restrict__ b1,
    const float* __restrict__ w2, const float* __restrict__ b2,
    float* __restrict__ x0, unsigned short* __restrict__ h2b,
    unsigned* __restrict__ gfeatU)
{
  __shared__ unsigned gmax[32];
  int tid = threadIdx.x;
  if (tid < 32) gmax[tid] = 0u;
  __syncthreads();
  int base = blockIdx.x*512;        // 512 points per block (never straddles batch)
  int b = base >> 12;
  int p0 = base + tid, p1 = base + 256 + tid;
  int n0 = p0 & 4095, n1 = p1 & 4095;
  int gy = blockIdx.y;              // outputs [gy*32, gy*32+32)
  int lane = tid & 63;
  float h1a[64], h1b[64];
  {
    const float* pA = in_pc + (size_t)p0*3;
    const float* pB = in_pc + (size_t)p1*3;
    float ax=pA[0], ay=pA[1], az=pA[2];
    float bx=pB[0], by=pB[1], bz=pB[2];
    #pragma unroll
    for (int c=0;c<64;c++){
      float w0=w1[c*3], w1v=w1[c*3+1], w2v=w1[c*3+2], bb=b1[c];
      h1a[c] = fmaxf(w0*ax + w1v*ay + w2v*az + bb, 0.f);
      h1b[c] = fmaxf(w0*bx + w1v*by + w2v*bz + bb, 0.f);
    }
  }
  #pragma unroll
  for (int jj=0;jj<4;jj++){
    unsigned short hpA[8], hpB[8];
    #pragma unroll
    for (int j=0;j<8;j++){
      int o = gy*32 + jj*8 + j;
      float bias = b2[o];
      float a = bias, d = bias;
      #pragma unroll
      for (int c=0;c<64;c++){
        float wv = w2[o*64+c];
        a += wv*h1a[c];
        d += wv*h1b[c];
      }
      a = fmaxf(a, 0.f); d = fmaxf(d, 0.f);
      float* xr = x0 + ((size_t)b*256 + o)*4096;
      xr[n0] = a; xr[n1] = d;
      hpA[j] = f2bf(a); hpB[j] = f2bf(d);
      float m = fmaxf(a, d);
      #pragma unroll
      for (int off=32; off; off>>=1) m = fmaxf(m, __shfl_xor(m, off));
      if (lane==0) atomicMax(&gmax[jj*8+j], __float_as_uint(m));
    }
    if (EMIT_H2){
      *(uint4*)&h2b[(size_t)p0*128 + gy*32 + jj*8] = *(const uint4*)hpA;
      *(uint4*)&h2b[(size_t)p1*128 + gy*32 + jj*8] = *(const uint4*)hpB;
    }
  }
  __syncthreads();
  if (tid < 32) atomicMax(&gfeatU[b*128 + gy*32 + tid], gmax[tid]);
}

// ------- x0 second half broadcast (8192 blocks) + gcon (4 blocks), fused -------
__global__ __launch_bounds__(256) void bcast_gcon(
    const unsigned* __restrict__ gfeatU, float* __restrict__ x0,
    const float* __restrict__ w3, const float* __restrict__ b3,
    float* __restrict__ gcon)
{
  __shared__ float gf[2048];
  int tid = threadIdx.x;
  if (blockIdx.x < 8192){
    unsigned U = blockIdx.x*256 + tid;   // over 16*128*1024 float4
    int n4 = U & 1023;
    int c  = (U >> 10) & 127;
    int b  = U >> 17;
    float g = __uint_as_float(gfeatU[b*128+c]);
    float4 v = {g,g,g,g};
    ((float4*)x0)[(((size_t)b*256 + 128 + c)*4096)/4 + n4] = v;
  } else {
    for (int i=tid;i<2048;i+=256) gf[i] = __uint_as_float(gfeatU[i]);
    __syncthreads();
    int o = (blockIdx.x - 8192)*256 + tid;
    float bias = b3[o];
    float acc[16];
    #pragma unroll
    for (int b=0;b<16;b++) acc[b]=bias;
    for (int c=0;c<128;c++){
      float wv = w3[(size_t)o*256 + 128 + c];
      #pragma unroll
      for (int b=0;b<16;b++) acc[b] += gf[b*128+c]*wv;
    }
    #pragma unroll
    for (int b=0;b<16;b++) gcon[b*1024+o] = acc[b];
  }
}

// ---------------- w3 f32 -> bf16 pre-pass ----------------
__global__ __launch_bounds__(256) void w3_cvt(
    const float* __restrict__ w3, unsigned* __restrict__ w3bf)
{
  int i = blockIdx.x*256 + threadIdx.x;   // over 131072 float2
  float2 v = ((const float2*)w3)[i];
  w3bf[i] = (unsigned)f2bf(v.x) | ((unsigned)f2bf(v.y)<<16);
}

// ------- conv3 MFMA GEMM (256n x 128k)x(128k -> 1024o) + relu + max-pool -------
__global__ __launch_bounds__(512) void conv3_pool(
    const unsigned short* __restrict__ h2b, const unsigned short* __restrict__ w3b,
    const float* __restrict__ gcon, unsigned* __restrict__ pooled)
{
  __shared__ unsigned short Al[256*128];
  __shared__ unsigned short Bl[256*128];
  int mt = blockIdx.x, b = blockIdx.y;
  int tid = threadIdx.x;
  { // stage A (bf16 [n][c]) — resident across nt loop
    const uint4* src = (const uint4*)(h2b + ((size_t)b*4096 + mt*256)*128);
    #pragma unroll
    for (int i=0;i<8;i++){
      int idx = i*512 + tid;
      int r = idx>>4, kc = idx&15;
      uint4 v = src[(size_t)r*16 + kc];
      int byte = (r*256 + kc*16) ^ ((r&7)<<4);
      *(uint4*)((char*)Al + byte) = v;
    }
  }
  int lane = tid & 63, wid = tid >> 6;
  int wm = wid >> 2, wn = wid & 3;       // 2x4 waves, each 128m x 64n
  int mbase = wm*128, nbase = wn*64;
  for (int nt=0; nt<4; nt++){
    if (nt) __syncthreads();
    { // stage B
      #pragma unroll
      for (int i=0;i<8;i++){
        int idx = i*512 + tid;
        int c = idx>>4, kc = idx&15;
        uint4 v = *(const uint4*)(w3b + ((size_t)(nt*256+c)*256 + kc*8));
        int byte = (c*256 + kc*16) ^ ((c&7)<<4);
        *(uint4*)((char*)Bl + byte) = v;
      }
    }
    __syncthreads();
    f32x4 acc[8][4] = {};
    #pragma unroll
    for (int ks=0;ks<4;ks++){
      int kb = (ks*32 + (lane>>4)*8)*2;
      short8 af[8], bfr[4];
      #pragma unroll
      for (int mi=0;mi<8;mi++){
        int row = mbase + mi*16 + (lane&15);
        af[mi] = *(const short8*)((const char*)Al + ((row*256 + kb) ^ ((row&7)<<4)));
      }
      #pragma unroll
      for (int ni=0;ni<4;ni++){
        int col = nbase + ni*16 + (lane&15);
        bfr[ni] = *(const short8*)((const char*)Bl + ((col*256 + kb) ^ ((col&7)<<4)));
      }
      #pragma unroll
      for (int mi=0;mi<8;mi++){
        #pragma unroll
        for (int ni=0;ni<4;ni++)
          acc[mi][ni] = __builtin_amdgcn_mfma_f32_16x16x32_bf16(af[mi], bfr[ni], acc[mi][ni], 0,0,0);
      }
    }
    #pragma unroll
    for (int ni=0;ni<4;ni++){
      int o = nt*256 + nbase + ni*16 + (lane&15);
      float g = gcon[b*1024 + o];
      float m = 0.f;
      #pragma unroll
      for (int mi=0;mi<8;mi++){
        f32x4 a = acc[mi][ni];
        #pragma unroll
        for (int r=0;r<4;r++){ float v = a[r]+g; m = fmaxf(m, v); }
      }
      m = fmaxf(m, 0.f);
      m = fmaxf(m, __shfl_xor(m, 16));
      m = fmaxf(m, __shfl_xor(m, 32));
      if (lane < 16) atomicMax(&pooled[(size_t)b*1024+o], __float_as_uint(m));
    }
  }
}

// ---------------- fallback conv3 + max-pool: block per (b, 8 outputs) ----------------
__global__ __launch_bounds__(256) void conv3n(
    const float* __restrict__ x0, const unsigned* __restrict__ gfeatU,
    const float* __restrict__ w3, const float* __restrict__ b3,
    unsigned* __restrict__ pooled)
{
  __shared__ float wrow[8][256];
  int b = blockIdx.x >> 7, og = (blockIdx.x & 127)*8, tid = threadIdx.x;
  for (int i=tid;i<2048;i+=256){ int j=i>>8, c=i&255; wrow[j][c]=w3[(size_t)(og+j)*256+c]; }
  __syncthreads();
  float gconst[8];
  #pragma unroll
  for (int j=0;j<8;j++){
    float g = b3[og+j];
    for (int c=0;c<128;c++) g += __uint_as_float(gfeatU[b*128+c])*wrow[j][128+c];
    gconst[j] = g;
  }
  const float* xb = x0 + (size_t)b*256*4096;
  float m[8];
  #pragma unroll
  for (int j=0;j<8;j++) m[j]=0.f;
  for (int n=tid;n<4096;n+=256){
    float v[8];
    #pragma unroll
    for (int j=0;j<8;j++) v[j]=gconst[j];
    for (int c=0;c<128;c++){
      float xv = xb[(size_t)c*4096 + n];
      #pragma unroll
      for (int j=0;j<8;j++) v[j] += xv*wrow[j][c];
    }
    #pragma unroll
    for (int j=0;j<8;j++) m[j] = fmaxf(m[j], v[j]);
  }
  #pragma unroll
  for (int j=0;j<8;j++){
    float v = m[j];
    for (int off=32; off; off>>=1) v = fmaxf(v, __shfl_xor(v, off));
    if ((tid&63)==0) atomicMax(&pooled[(size_t)b*1024+og+j], __float_as_uint(v));
  }
}

// ------- fc: one wave per output o, all 16 batches in registers; W read once -------
template<bool RELU>
__global__ __launch_bounds__(256) void fc_wave16(
    const float* __restrict__ A, const float* __restrict__ W,
    const float* __restrict__ bias, float* __restrict__ out,
    float* __restrict__ out2, int K, int O)
{
  int lane = threadIdx.x & 63, w = threadIdx.x >> 6;
  int o = blockIdx.x*4 + w;
  const float* Wr = W + (size_t)o*K;
  float acc[16];
  #pragma unroll
  for (int b=0;b<16;b++) acc[b]=0.f;
  for (int k = lane*4; k < K; k += 256){
    float4 wv = *(const float4*)&Wr[k];
    #pragma unroll
    for (int b=0;b<16;b++){
      float4 av = *(const float4*)&A[(size_t)b*K + k];
      acc[b] += wv.x*av.x + wv.y*av.y + wv.z*av.z + wv.w*av.w;
    }
  }
  #pragma unroll
  for (int b=0;b<16;b++){
    float v = acc[b];
    #pragma unroll
    for (int off=32; off; off>>=1) v += __shfl_xor(v, off);
    if (lane==0){
      v += bias[o];
      if (RELU) v = fmaxf(v, 0.f);
      out[(size_t)b*O+o] = v;
      if (out2) out2[(size_t)b*O+o] = v;
    }
  }
}

// ---------------- LayerNorm over 6144 per batch row ----------------
__global__ __launch_bounds__(256) void lnorm(
    const float* __restrict__ h3, const float* __restrict__ g,
    const float* __restrict__ be, float* __restrict__ outf,
    float* __restrict__ outb)
{
  int b = blockIdx.x, tid = threadIdx.x;
  const float* x = h3 + b*6144;
  float s=0.f, s2=0.f;
  for (int i=tid;i<6144;i+=256){ float v=x[i]; s+=v; s2+=v*v; }
  for (int off=32; off; off>>=1){ s += __shfl_xor(s,off); s2 += __shfl_xor(s2,off); }
  __shared__ float red[8];
  int lane = tid&63, wid = tid>>6;
  if (lane==0){ red[wid]=s; red[4+wid]=s2; }
  __syncthreads();
  s  = red[0]+red[1]+red[2]+red[3];
  s2 = red[4]+red[5]+red[6]+red[7];
  float mu  = s * (1.f/6144.f);
  float var = s2 * (1.f/6144.f) - mu*mu;
  float inv = rsqrtf(var + 1e-5f);
  for (int i=tid;i<6144;i+=256){
    float v = (x[i]-mu)*inv*g[i] + be[i];
    outf[b*6144+i] = v;
    outb[b*6144+i] = v;
  }
}

// ---------------- chamfer: merged d1 (blocks 0..1023) + d2 (1024..1535) ----------------
__global__ __launch_bounds__(256) void chamfer_all(
    const float* __restrict__ in_pc, const float* __restrict__ opc,
    unsigned* __restrict__ d1m, unsigned* __restrict__ d2m)
{
  __shared__ float sbuf[3072];
  int bid = blockIdx.x, tid = threadIdx.x;
  if (bid < 1024){
    int xt = bid & 15, b = (bid >> 4) & 15, mt = bid >> 8;
    float* qx = sbuf; float* qy = sbuf+512; float* qz = sbuf+1024;
    const float* qb = opc + b*6144 + mt*1536;
    for (int i=tid;i<512;i+=256){ qx[i]=qb[i*3]; qy[i]=qb[i*3+1]; qz[i]=qb[i*3+2]; }
    __syncthreads();
    int n = xt*256 + tid;
    size_t base = ((size_t)b*4096 + n)*3;
    float px=in_pc[base], py=in_pc[base+1], pz=in_pc[base+2];
    float mn = 3.0e38f;
    for (int m4=0;m4<128;m4++){
      float4 X = *(const float4*)&qx[m4*4];
      float4 Y = *(const float4*)&qy[m4*4];
      float4 Z = *(const float4*)&qz[m4*4];
      float dx,dy,dz,d;
      dx=px-X.x; dy=py-Y.x; dz=pz-Z.x; d=dx*dx+dy*dy+dz*dz; mn=fminf(mn,d);
      dx=px-X.y; dy=py-Y.y; dz=pz-Z.y; d=dx*dx+dy*dy+dz*dz; mn=fminf(mn,d);
      dx=px-X.z; dy=py-Y.z; dz=pz-Z.z; d=dx*dx+dy*dy+dz*dz; mn=fminf(mn,d);
      dx=px-X.w; dy=py-Y.w; dz=pz-Z.w; d=dx*dx+dy*dy+dz*dz; mn=fminf(mn,d);
    }
    atomicMin(&d1m[b*4096+n], __float_as_uint(mn));
  } else {
    int r = bid - 1024;
    int xt = r & 7, b = (r >> 3) & 15, nt = r >> 7;
    float* sx = sbuf; float* sy = sbuf+1024; float* sz = sbuf+2048;
    size_t base = ((size_t)b*4096 + nt*1024)*3;
    for (int i=tid;i<1024;i+=256){
      sx[i]=in_pc[base+i*3]; sy[i]=in_pc[base+i*3+1]; sz[i]=in_pc[base+i*3+2];
    }
    __syncthreads();
    int m = xt*256 + tid;
    const float* q = opc + b*6144 + m*3;
    float qxv=q[0], qyv=q[1], qzv=q[2];
    float mn = 3.0e38f;
    for (int n4=0;n4<256;n4++){
      float4 X = *(const float4*)&sx[n4*4];
      float4 Y = *(const float4*)&sy[n4*4];
      float4 Z = *(const float4*)&sz[n4*4];
      float dx,dy,dz,d;
      dx=qxv-X.x; dy=qyv-Y.x; dz=qzv-Z.x; d=dx*dx+dy*dy+dz*dz; mn=fminf(mn,d);
      dx=qxv-X.y; dy=qyv-Y.y; dz=qzv-Z.y; d=dx*dx+dy*dy+dz*dz; mn=fminf(mn,d);
      dx=qxv-X.z; dy=qyv-Y.z; dz=qzv-Z.z; d=dx*dx+dy*dy+dz*dz; mn=fminf(mn,d);
      dx=qxv-X.w; dy=qyv-Y.w; dz=qzv-Z.w; d=dx*dx+dy*dy+dz*dz; mn=fminf(mn,d);
    }
    atomicMin(&d2m[b*2048+m], __float_as_uint(mn));
  }
}

// ---------------- deterministic loss reduction ----------------
__global__ __launch_bounds__(256) void sum_part(
    const unsigned* __restrict__ d1m, const unsigned* __restrict__ d2m,
    float* __restrict__ ps)
{
  int bid = blockIdx.x, tid = threadIdx.x;
  const unsigned* src = (bid<64) ? (d1m + bid*1024) : (d2m + (size_t)(bid-64)*1024);
  float s = 0.f;
  for (int i=tid;i<1024;i+=256) s += __uint_as_float(src[i]);
  for (int off=32; off; off>>=1) s += __shfl_xor(s,off);
  __shared__ float red[4];
  if ((tid&63)==0) red[tid>>6]=s;
  __syncthreads();
  if (tid==0) ps[bid] = red[0]+red[1]+red[2]+red[3];
}

__global__ void loss_k(const float* __restrict__ ps, float* __restrict__ out){
  int tid = threadIdx.x;  // 128 threads
  float v = 0.f;
  if (tid < 64) v = ps[tid] * (1.0f/65536.0f);
  else if (tid < 96) v = ps[tid] * (1.0f/32768.0f);
  for (int off=32; off; off>>=1) v += __shfl_xor(v,off);
  __shared__ float red[2];
  if ((tid&63)==0) red[tid>>6]=v;
  __syncthreads();
  if (tid==0) out[0] = red[0]+red[1];
}

// ---------------- launch ----------------
extern "C" void kernel_launch(void* const* d_in, const int* in_sizes, int n_in,
                              void* d_out, int out_size, void* d_ws, size_t ws_size,
                              hipStream_t stream)
{
  (void)in_sizes; (void)n_in; (void)out_size;
  const float* in_pc = (const float*)d_in[0];
  const float* w1   = (const float*)d_in[1];
  const float* b1   = (const float*)d_in[2];
  const float* w2   = (const float*)d_in[3];
  const float* b2   = (const float*)d_in[4];
  const float* w3   = (const float*)d_in[5];
  const float* b3   = (const float*)d_in[6];
  const float* wenc = (const float*)d_in[7];
  const float* benc = (const float*)d_in[8];
  const float* wf1  = (const float*)d_in[9];
  const float* bfc1 = (const float*)d_in[10];
  const float* wf2  = (const float*)d_in[11];
  const float* bfc2 = (const float*)d_in[12];
  const float* wf3  = (const float*)d_in[13];
  const float* bfc3 = (const float*)d_in[14];
  const float* lng  = (const float*)d_in[15];
  const float* lnb  = (const float*)d_in[16];
  float* out = (float*)d_out;

  bool big = ws_size >= (size_t)(H2_BYTES + 2*1024*1024);
  char* ws = (char*)d_ws;
  unsigned short* h2b = (unsigned short*)ws;           // big path only
  char* small = ws + (big ? H2_BYTES : 0);

  unsigned* gfeatU = (unsigned*)(small + OFF_GFEAT);
  float* pooled = (float*)(small + OFF_POOL);
  float* gcon = (float*)(small + OFF_GCON);
  float* emb  = (float*)(small + OFF_EMB);
  float* hd1  = (float*)(small + OFF_HD1);
  float* hd2  = (float*)(small + OFF_HD2);
  float* h3   = (float*)(small + OFF_H3);
  float* opc  = (float*)(small + OFF_OPC);
  unsigned* d1m = (unsigned*)(small + OFF_D1M);
  unsigned* d2m = (unsigned*)(small + OFF_D2M);
  float* ps   = (float*)(small + OFF_PS);
  unsigned short* w3b = (unsigned short*)(small + OFF_W3BF);

  hipMemsetAsync(small + OFF_GFEAT, 0, 8192 + 65536, stream);      // gfeat + pooled = 0
  hipMemsetAsync(small + OFF_D1M, 0x7F, 262144 + 131072, stream);  // d1m + d2m ~ +inf

  if (big){
    w3_cvt<<<512, 256, 0, stream>>>(w3, (unsigned*)w3b);
    conv12<true ><<<dim3(128,4), 256, 0, stream>>>(in_pc, w1, b1, w2, b2, out, h2b, gfeatU);
  } else {
    conv12<false><<<dim3(128,4), 256, 0, stream>>>(in_pc, w1, b1, w2, b2, out, nullptr, gfeatU);
  }
  bcast_gcon<<<8196, 256, 0, stream>>>(gfeatU, out, w3, b3, gcon);
  if (big){
    conv3_pool<<<dim3(16,16), 512, 0, stream>>>(h2b, w3b, gcon, (unsigned*)pooled);
  } else {
    conv3n<<<2048, 256, 0, stream>>>(out, gfeatU, w3, b3, (unsigned*)pooled);
  }
  fc_wave16<false><<<64,   256, 0, stream>>>(pooled, wenc, benc, emb, out + OUT_EMB, 1024, 256);
  fc_wave16<true ><<<128,  256, 0, stream>>>(emb, wf1, bfc1, hd1, nullptr, 256, 512);
  fc_wave16<true ><<<256,  256, 0, stream>>>(hd1, wf2, bfc2, hd2, nullptr, 512, 1024);
  fc_wave16<false><<<1536, 256, 0, stream>>>(hd2, wf3, bfc3, h3, nullptr, 1024, 6144);
  lnorm<<<16, 256, 0, stream>>>(h3, lng, lnb, opc, out + OUT_OPC);
  chamfer_all<<<1536, 256, 0, stream>>>(in_pc, opc, d1m, d2m);
  sum_part<<<96, 256, 0, stream>>>(d1m, d2m, ps);
  loss_k<<<1, 128, 0, stream>>>(ps, out + OUT_LOSS);
}